// Round 4
// baseline (2815.126 us; speedup 1.0000x reference)
//
#include <hip/hip_runtime.h>
#include <cstdint>
#include <cstddef>

typedef float f4 __attribute__((ext_vector_type(4)));

#define N_NODES 2048
#define BATCH 16
#define LSEQ 12
#define MDIM 112
#define GDIM 448                   // 4*M
#define KC 35                      // reduced contraction: 3 hist + 16 tid + 16 diw
#define NCOLS_C 6784               // KC*BATCH*LSEQ = 6720 padded to 53*128

__device__ __forceinline__ float sigmoidf_(float x) { return 1.0f / (1.0f + expf(-x)); }

// ---------------------------------------------------------------------------
// K1: build compact Xc[k][j], j=(b*12+l)*35+c. c:0..2 hist ch, 3..18 tid emb,
// 19..34 diw emb. Pad cols 6720..6783 zeroed.
// ---------------------------------------------------------------------------
__global__ void build_xc_kernel(const float* __restrict__ hist,
                                const float* __restrict__ tid_emb,
                                const float* __restrict__ diw_emb,
                                float* __restrict__ Xc)
{
    int flat = blockIdx.x * 256 + threadIdx.x;
    const int total = N_NODES * NCOLS_C;
    if (flat >= total) return;
    int j = flat % NCOLS_C;
    int k = flat / NCOLS_C;
    if (j >= KC * BATCH * LSEQ) { Xc[flat] = 0.f; return; }
    int c  = j % KC;
    int bl = j / KC;                         // b*12+l
    const float* h = hist + ((size_t)bl * N_NODES + k) * 3;
    float v;
    if (c < 3) {
        v = h[c];
    } else if (c < 19) {
        int ti = (int)(h[1] * 288.0f);       // truncating cast, matches reference
        v = tid_emb[ti * 16 + (c - 3)];
    } else {
        int di = (int)(h[2] * 7.0f);
        v = diw_emb[di * 16 + (c - 19)];
    }
    Xc[flat] = v;
}

// ---------------------------------------------------------------------------
// K2: A_dy = softmax(relu(E @ E^T), axis=1), one block per row, with fused
// epilogue computing node_a[n,:] = sum_k Ady[n,k]*node_emb[k,:] and
// rs[n] = sum_k Ady[n,k] straight from the LDS row (saves a 16.8MB re-read).
// ---------------------------------------------------------------------------
__global__ void adaptive_adj_kernel(const float* __restrict__ E,
                                    const float* __restrict__ node_emb,
                                    float* __restrict__ Ady,
                                    float* __restrict__ node_a,
                                    float* __restrict__ rs)
{
    __shared__ float sbuf[N_NODES];
    __shared__ float red[256];
    const int n = blockIdx.x;
    const int tid = threadIdx.x;
    float en[16];
#pragma unroll
    for (int i = 0; i < 16; ++i) en[i] = E[n * 16 + i];
    float lmax = -3.4e38f;
    for (int k = tid; k < N_NODES; k += 256) {
        const float* ek = E + k * 16;
        float d = 0.f;
#pragma unroll
        for (int i = 0; i < 16; ++i) d += en[i] * ek[i];
        d = fmaxf(d, 0.0f);
        sbuf[k] = d;
        lmax = fmaxf(lmax, d);
    }
    red[tid] = lmax; __syncthreads();
    for (int s = 128; s > 0; s >>= 1) {
        if (tid < s) red[tid] = fmaxf(red[tid], red[tid + s]);
        __syncthreads();
    }
    float mx = red[0];
    __syncthreads();
    float lsum = 0.f;
    for (int k = tid; k < N_NODES; k += 256) {
        float e = expf(sbuf[k] - mx);
        sbuf[k] = e;
        lsum += e;
    }
    red[tid] = lsum; __syncthreads();
    for (int s = 128; s > 0; s >>= 1) {
        if (tid < s) red[tid] += red[tid + s];
        __syncthreads();
    }
    float tot = red[0];
    __syncthreads();

    float p[17];
#pragma unroll
    for (int i = 0; i < 17; ++i) p[i] = 0.f;
    for (int k = tid; k < N_NODES; k += 256) {
        float a = sbuf[k] / tot;
        Ady[(size_t)n * N_NODES + k] = a;
        const float* e = node_emb + k * 16;
        p[16] += a;
#pragma unroll
        for (int i = 0; i < 16; ++i) p[i] += a * e[i];
    }
    for (int e = 0; e < 17; ++e) {
        red[tid] = p[e]; __syncthreads();
        for (int s = 128; s > 0; s >>= 1) {
            if (tid < s) red[tid] += red[tid + s];
            __syncthreads();
        }
        if (tid == 0) {
            if (e < 16) node_a[n * 16 + e] = red[0];
            else rs[n] = red[0];
        }
        __syncthreads();
    }
}

// ---------------------------------------------------------------------------
// K3: per-row  node_a[n,0:16] = sum_k A[n,k]*node_emb[k,:],  rs[n] = sum_k A[n,k]
// (used for the predefined adjacency input)
// ---------------------------------------------------------------------------
__global__ void node_rs_kernel(const float* __restrict__ A,
                               const float* __restrict__ node_emb,
                               float* __restrict__ node_a, float* __restrict__ rs)
{
    __shared__ float red[256];
    const int n = blockIdx.x;
    const int tid = threadIdx.x;
    float p[17];
#pragma unroll
    for (int i = 0; i < 17; ++i) p[i] = 0.f;
    for (int k = tid; k < N_NODES; k += 256) {
        float a = A[(size_t)n * N_NODES + k];
        const float* e = node_emb + k * 16;
        p[16] += a;
#pragma unroll
        for (int i = 0; i < 16; ++i) p[i] += a * e[i];
    }
    for (int e = 0; e < 17; ++e) {
        red[tid] = p[e]; __syncthreads();
        for (int s = 128; s > 0; s >>= 1) {
            if (tid < s) red[tid] += red[tid + s];
            __syncthreads();
        }
        if (tid == 0) {
            if (e < 16) node_a[n * 16 + e] = red[0];
            else rs[n] = red[0];
        }
        __syncthreads();
    }
}

// ---------------------------------------------------------------------------
// K4: pack effective weights per layer:
//   Wt[c][g]   = sum_{m<64} W_in[c,m]*W[m,g]          (c = 0..2)
//   Wt[3+e][g] = W[80+e, g]                           (e = 0..31, tid||diw rows)
//   bW1[g]     = sum_{m<64} b_in[m]*W[m,g]
// ---------------------------------------------------------------------------
__global__ void prep_wt_kernel(const float* __restrict__ W_in,
                               const float* __restrict__ b_in,
                               const float* __restrict__ W,
                               float* __restrict__ Wt, float* __restrict__ bW1)
{
    int g = blockIdx.x * 256 + threadIdx.x;
    if (g >= GDIM) return;
#pragma unroll
    for (int c = 0; c < 3; ++c) {
        float s = 0.f;
        for (int m = 0; m < 64; ++m) s += W_in[c * 64 + m] * W[(size_t)m * GDIM + g];
        Wt[c * GDIM + g] = s;
    }
    float sb = 0.f;
    for (int m = 0; m < 64; ++m) sb += b_in[m] * W[(size_t)m * GDIM + g];
    bW1[g] = sb;
    for (int e = 0; e < 32; ++e)
        Wt[(3 + e) * GDIM + g] = W[(size_t)(80 + e) * GDIM + g];
}

// ---------------------------------------------------------------------------
// K5: gate constants  Gc[n,g] = sum_e node_a[n,e]*W[64+e,g] + rs[n]*bW1[g] + bg[g]
// ---------------------------------------------------------------------------
__global__ void gc_kernel(const float* __restrict__ node_a, const float* __restrict__ rs,
                          const float* __restrict__ W, const float* __restrict__ bW1,
                          const float* __restrict__ bg, float* __restrict__ Gc)
{
    int idx = blockIdx.x * 256 + threadIdx.x;
    if (idx >= N_NODES * GDIM) return;
    int g = idx % GDIM;
    int n = idx / GDIM;
    float s = bg[g] + rs[n] * bW1[g];
    const float* na = node_a + n * 16;
#pragma unroll
    for (int e = 0; e < 16; ++e) s += na[e] * W[(size_t)(64 + e) * GDIM + g];
    Gc[idx] = s;
}

// ---------------------------------------------------------------------------
// K6: stacked fp32 SGEMM  C[4096][ncols] = [A0;A1][4096][2048] @ B[2048][ncols]
// 128x128 tile, BK=16, DOUBLE-BUFFERED LDS -> one barrier per K-tile.
// Row tiles 0..15 use A0 (adj), 16..31 use A1 (Ady).
// ---------------------------------------------------------------------------
#define STAGE(BUF)                                            \
    {                                                         \
        _Pragma("unroll")                                     \
        for (int i = 0; i < 4; ++i) {                         \
            As[BUF][akc + i][arow]      = a0[i];              \
            As[BUF][akc + i][arow + 64] = a1[i];              \
        }                                                     \
        *(f4*)&Bs[BUF][brow][bjc]     = b0;                   \
        *(f4*)&Bs[BUF][brow + 8][bjc] = b1;                   \
    }

#define COMPUTE(BUF)                                          \
    {                                                         \
        _Pragma("unroll")                                     \
        for (int kk = 0; kk < 16; ++kk) {                     \
            f4 aA = *(const f4*)&As[BUF][kk][ty * 4];         \
            f4 aB = *(const f4*)&As[BUF][kk][64 + ty * 4];    \
            f4 bA = *(const f4*)&Bs[BUF][kk][tx * 4];         \
            f4 bB = *(const f4*)&Bs[BUF][kk][64 + tx * 4];    \
            _Pragma("unroll")                                 \
            for (int i = 0; i < 4; ++i) {                     \
                acc[0][0][i] += aA[i] * bA;                   \
                acc[0][1][i] += aA[i] * bB;                   \
                acc[1][0][i] += aB[i] * bA;                   \
                acc[1][1][i] += aB[i] * bB;                   \
            }                                                 \
        }                                                     \
    }

__global__ __launch_bounds__(256) void sgemm2_kernel(const float* __restrict__ A0,
                                                     const float* __restrict__ A1,
                                                     const float* __restrict__ B,
                                                     float* __restrict__ C,
                                                     int ncols)
{
    __shared__ float As[2][16][132];
    __shared__ float Bs[2][16][128];
    const int tid = threadIdx.x;
    const int tx = tid & 15;
    const int ty = tid >> 4;
    const int mt = blockIdx.y;                  // 0..31
    const float* A = (mt < 16) ? A0 : A1;
    const int m0 = (mt & 15) * 128;             // row within selected A
    const size_t crow = (size_t)mt * 128;       // row in stacked C (0..4095)
    const int j0 = blockIdx.x * 128;

    const int arow = tid >> 2;
    const int akc  = (tid & 3) << 2;
    const int brow = tid >> 5;
    const int bjc  = (tid & 31) << 2;

    const size_t ldb = (size_t)ncols;
    const float* Aptr0 = A + (size_t)(m0 + arow) * 2048 + akc;
    const float* Aptr1 = A + (size_t)(m0 + arow + 64) * 2048 + akc;
    const float* Bptr0 = B + (size_t)brow * ldb + j0 + bjc;
    const float* Bptr1 = B + (size_t)(brow + 8) * ldb + j0 + bjc;

    f4 a0 = *(const f4*)Aptr0;
    f4 a1 = *(const f4*)Aptr1;
    f4 b0 = *(const f4*)Bptr0;
    f4 b1 = *(const f4*)Bptr1;

    f4 acc[2][2][4];
#pragma unroll
    for (int p = 0; p < 2; ++p)
#pragma unroll
        for (int q = 0; q < 2; ++q)
#pragma unroll
            for (int i = 0; i < 4; ++i)
#pragma unroll
                for (int e = 0; e < 4; ++e) acc[p][q][i][e] = 0.f;

    for (int kt = 0; kt < 2048; kt += 32) {
        // -------- tile kt --------
        STAGE(0)
        __syncthreads();
        a0 = *(const f4*)(Aptr0 + kt + 16);                    // always valid (kt<=2016)
        a1 = *(const f4*)(Aptr1 + kt + 16);
        b0 = *(const f4*)(Bptr0 + (size_t)(kt + 16) * ldb);
        b1 = *(const f4*)(Bptr1 + (size_t)(kt + 16) * ldb);
        COMPUTE(0)
        // -------- tile kt+16 --------
        STAGE(1)
        __syncthreads();
        if (kt + 32 < 2048) {
            a0 = *(const f4*)(Aptr0 + kt + 32);
            a1 = *(const f4*)(Aptr1 + kt + 32);
            b0 = *(const f4*)(Bptr0 + (size_t)(kt + 32) * ldb);
            b1 = *(const f4*)(Bptr1 + (size_t)(kt + 32) * ldb);
        }
        COMPUTE(1)
    }

#pragma unroll
    for (int p = 0; p < 2; ++p)
#pragma unroll
        for (int i = 0; i < 4; ++i) {
            size_t row = crow + p * 64 + ty * 4 + i;
            *(f4*)&C[row * ldb + j0 + tx * 4]      = acc[p][0][i];
            *(f4*)&C[row * ldb + j0 + 64 + tx * 4] = acc[p][1][i];
        }
}

// ---------------------------------------------------------------------------
// K7: fused gates (35-term contraction) + LSTM c-recurrence over L=12.
// blockIdx.z selects layer (0: predefined adj, 1: dynamic), reading the
// corresponding half of the stacked XA.
// ---------------------------------------------------------------------------
__global__ __launch_bounds__(256) void lstm3_kernel(const float* __restrict__ XAall,
                                                    const float* __restrict__ Wt_pre,
                                                    const float* __restrict__ Wt_dy,
                                                    const float* __restrict__ Gc_pre,
                                                    const float* __restrict__ Gc_dy,
                                                    float* __restrict__ H)
{
    __shared__ float xa_s[32][37];
    __shared__ float c_s[32][113];
    __shared__ float t1_s[32][113];
    const int tid  = threadIdx.x;
    const int co   = tid >> 6;      // 0:i 1:f 2:g 3:o
    const int lane = tid & 63;
    const int mt   = lane & 15;
    const int nt   = lane >> 4;
    const int n0   = blockIdx.x * 32;
    const int b    = blockIdx.y;
    const int z    = blockIdx.z;

    const float* XA   = XAall + (size_t)z * N_NODES * NCOLS_C;
    const float* Wt   = z ? Wt_dy : Wt_pre;
    const float* Gc   = z ? Gc_dy : Gc_pre;
    float*       Hout = H + (size_t)z * BATCH * N_NODES * MDIM;

    for (int e = tid; e < 32 * 113; e += 256) (&c_s[0][0])[e] = 0.f;

    const float* Wc  = Wt + co * 112;
    const float* GcB = Gc + co * 112;

    float acc[8][7];

    for (int t = 0; t < LSEQ; ++t) {
        __syncthreads();
        for (int e = tid; e < 32 * KC; e += 256) {
            int n = e / KC;
            int c = e - n * KC;
            xa_s[n][c] = XA[(size_t)(n0 + n) * NCOLS_C + (b * LSEQ + t) * KC + c];
        }
        __syncthreads();
#pragma unroll
        for (int nn = 0; nn < 8; ++nn)
#pragma unroll
            for (int mm = 0; mm < 7; ++mm)
                acc[nn][mm] = GcB[(size_t)(n0 + nt * 8 + nn) * GDIM + mt + mm * 16];
#pragma unroll 5
        for (int k = 0; k < KC; ++k) {
            float w[7];
#pragma unroll
            for (int mm = 0; mm < 7; ++mm) w[mm] = Wc[k * GDIM + mt + mm * 16];
#pragma unroll
            for (int nn = 0; nn < 8; ++nn) {
                float a = xa_s[nt * 8 + nn][k];
#pragma unroll
                for (int mm = 0; mm < 7; ++mm) acc[nn][mm] = fmaf(a, w[mm], acc[nn][mm]);
            }
        }
        if (co == 0) {        // i: stash sigmoid(i)
#pragma unroll
            for (int nn = 0; nn < 8; ++nn)
#pragma unroll
                for (int mm = 0; mm < 7; ++mm)
                    t1_s[nt * 8 + nn][mt + mm * 16] = sigmoidf_(acc[nn][mm]);
        } else if (co == 1) { // f: c *= sigmoid(f)
#pragma unroll
            for (int nn = 0; nn < 8; ++nn)
#pragma unroll
                for (int mm = 0; mm < 7; ++mm)
                    c_s[nt * 8 + nn][mt + mm * 16] *= sigmoidf_(acc[nn][mm]);
        }
        __syncthreads();
        if (co == 2) {        // g: c += tanh(g) * sigmoid(i)
#pragma unroll
            for (int nn = 0; nn < 8; ++nn)
#pragma unroll
                for (int mm = 0; mm < 7; ++mm)
                    c_s[nt * 8 + nn][mt + mm * 16] += tanhf(acc[nn][mm]) * t1_s[nt * 8 + nn][mt + mm * 16];
        }
        if (t == LSEQ - 1) {
            __syncthreads();
            if (co == 3) {    // o: h = sigmoid(o) * tanh(c)
#pragma unroll
                for (int nn = 0; nn < 8; ++nn)
#pragma unroll
                    for (int mm = 0; mm < 7; ++mm)
                        Hout[((size_t)b * N_NODES + n0 + nt * 8 + nn) * MDIM + mt + mm * 16]
                            = sigmoidf_(acc[nn][mm]) * tanhf(c_s[nt * 8 + nn][mt + mm * 16]);
            }
        }
    }
}

// ---------------------------------------------------------------------------
// K8: fused decoder (layers 1 and 2 identical -> weight folding).
// ---------------------------------------------------------------------------
__global__ void decode_kernel(const float* __restrict__ H,
                              const float* __restrict__ Wdec,
                              const float* __restrict__ bdec,
                              const float* __restrict__ Wout,
                              const float* __restrict__ bout,
                              float* __restrict__ out)
{
    int g = blockIdx.x * 256 + threadIdx.x;   // g = b*2048 + n
    if (g >= BATCH * N_NODES) return;
    int b = g >> 11;
    int n = g & 2047;
    const float* h0 = H + (size_t)g * MDIM;
    const float* h1 = H + (size_t)BATCH * N_NODES * MDIM + (size_t)g * MDIM;
    float x[12];
#pragma unroll
    for (int o = 0; o < 12; ++o) x[o] = bdec[o];
    for (int m = 0; m < MDIM; ++m) {
        float a0 = h0[m], a1 = h1[m];
#pragma unroll
        for (int o = 0; o < 12; ++o)
            x[o] += a0 * Wdec[(o * 3 + 0) * MDIM + m]
                  + a1 * (Wdec[(o * 3 + 1) * MDIM + m] + Wdec[(o * 3 + 2) * MDIM + m]);
    }
#pragma unroll
    for (int p = 0; p < 12; ++p) {
        float s = bout[p];
#pragma unroll
        for (int o = 0; o < 12; ++o) s += Wout[p * 12 + o] * x[o];
        out[((size_t)b * 12 + p) * N_NODES + n] = s;
    }
}

// ---------------------------------------------------------------------------
extern "C" void kernel_launch(void* const* d_in, const int* in_sizes, int n_in,
                              void* d_out, int out_size, void* d_ws, size_t ws_size,
                              hipStream_t stream)
{
    const float* hist   = (const float*)d_in[0];
    const float* adj    = (const float*)d_in[1];
    const float* node_e = (const float*)d_in[2];
    const float* tid_e  = (const float*)d_in[3];
    const float* diw_e  = (const float*)d_in[4];
    const float* W_in   = (const float*)d_in[5];
    const float* b_in   = (const float*)d_in[6];
    const float* W_pre  = (const float*)d_in[7];
    const float* b_pre  = (const float*)d_in[8];
    const float* E_dy   = (const float*)d_in[9];
    const float* W_dy   = (const float*)d_in[10];
    const float* b_dy   = (const float*)d_in[11];
    const float* W_dec  = (const float*)d_in[12];
    const float* b_dec  = (const float*)d_in[13];
    const float* W_out  = (const float*)d_in[14];
    const float* b_out  = (const float*)d_in[15];
    float* out = (float*)d_out;

    float* ws = (float*)d_ws;
    const size_t ADY_F = (size_t)N_NODES * N_NODES;           // 4.19M
    const size_t H_F   = (size_t)2 * BATCH * N_NODES * MDIM;  // 7.34M
    const size_t XC_F  = (size_t)N_NODES * NCOLS_C;           // 13.9M

    float* Ady    = ws;                     ws += ADY_F;
    float* H      = ws;                     ws += H_F;
    float* Xc     = ws;                     ws += XC_F;
    float* XA     = ws;                     ws += 2 * XC_F;   // stacked [4096][NCOLS_C]
    float* na_pre = ws;                     ws += (size_t)N_NODES * 16;
    float* na_dy  = ws;                     ws += (size_t)N_NODES * 16;
    float* rs_pre = ws;                     ws += N_NODES;
    float* rs_dy  = ws;                     ws += N_NODES;
    float* Wt_pre = ws;                     ws += (size_t)KC * GDIM;
    float* Wt_dy  = ws;                     ws += (size_t)KC * GDIM;
    float* bW_pre = ws;                     ws += GDIM;
    float* bW_dy  = ws;                     ws += GDIM;
    float* Gc_pre = ws;                     ws += (size_t)N_NODES * GDIM;
    float* Gc_dy  = ws;                     ws += (size_t)N_NODES * GDIM;

    build_xc_kernel<<<(int)((XC_F + 255) / 256), 256, 0, stream>>>(hist, tid_e, diw_e, Xc);
    adaptive_adj_kernel<<<N_NODES, 256, 0, stream>>>(E_dy, node_e, Ady, na_dy, rs_dy);
    node_rs_kernel<<<N_NODES, 256, 0, stream>>>(adj, node_e, na_pre, rs_pre);

    prep_wt_kernel<<<2, 256, 0, stream>>>(W_in, b_in, W_pre, Wt_pre, bW_pre);
    prep_wt_kernel<<<2, 256, 0, stream>>>(W_in, b_in, W_dy, Wt_dy, bW_dy);

    gc_kernel<<<(N_NODES * GDIM + 255) / 256, 256, 0, stream>>>(na_pre, rs_pre, W_pre, bW_pre, b_pre, Gc_pre);
    gc_kernel<<<(N_NODES * GDIM + 255) / 256, 256, 0, stream>>>(na_dy, rs_dy, W_dy, bW_dy, b_dy, Gc_dy);

    // both graph propagations in ONE stacked dispatch (M = 4096)
    sgemm2_kernel<<<dim3(NCOLS_C / 128, 32), 256, 0, stream>>>(adj, Ady, Xc, XA, NCOLS_C);

    // both layers' gate GEMM + recurrence in ONE dispatch (z = layer)
    lstm3_kernel<<<dim3(N_NODES / 32, BATCH, 2), 256, 0, stream>>>(
        XA, Wt_pre, Wt_dy, Gc_pre, Gc_dy, H);

    decode_kernel<<<(BATCH * N_NODES + 255) / 256, 256, 0, stream>>>(
        H, W_dec, b_dec, W_out, b_out, out);
}

// Round 5
// 1636.586 us; speedup vs baseline: 1.7201x; 1.7201x over previous
//
#include <hip/hip_runtime.h>
#include <hip/hip_bf16.h>
#include <cstdint>
#include <cstddef>

typedef float f4 __attribute__((ext_vector_type(4)));
typedef short s16x8 __attribute__((ext_vector_type(8)));   // 8 bf16 in 4 VGPRs (guide §3)

#define N_NODES 2048
#define BATCH 16
#define LSEQ 12
#define MDIM 112
#define GDIM 448                   // 4*M
#define KC 35                      // reduced contraction: 3 hist + 16 tid + 16 diw
#define NCOLS_X 6784               // KC*BATCH*LSEQ = 6720 padded to 53*128
#define KBIG 6144                  // 3 * 2048 (split-K: A1|A2|A3 vs X1;X2;X3)
#define NJ0 3456                   // chunk0 cols = 27*128
#define NJ1 3328                   // chunk1 cols = 26*128

#define GLDS16(SRC, DST)                                                        \
    __builtin_amdgcn_global_load_lds(                                           \
        (const __attribute__((address_space(1))) void*)(SRC),                   \
        (__attribute__((address_space(3))) void*)(DST), 16, 0, 0)

__device__ __forceinline__ float sigmoidf_(float x) { return 1.0f / (1.0f + expf(-x)); }

// ---------------------------------------------------------------------------
// K1: A_dy = softmax(relu(E @ E^T), axis=1) with fused node_a/rs epilogue.
// ---------------------------------------------------------------------------
__global__ void adaptive_adj_kernel(const float* __restrict__ E,
                                    const float* __restrict__ node_emb,
                                    float* __restrict__ Ady,
                                    float* __restrict__ node_a,
                                    float* __restrict__ rs)
{
    __shared__ float sbuf[N_NODES];
    __shared__ float red[256];
    const int n = blockIdx.x;
    const int tid = threadIdx.x;
    float en[16];
#pragma unroll
    for (int i = 0; i < 16; ++i) en[i] = E[n * 16 + i];
    float lmax = -3.4e38f;
    for (int k = tid; k < N_NODES; k += 256) {
        const float* ek = E + k * 16;
        float d = 0.f;
#pragma unroll
        for (int i = 0; i < 16; ++i) d += en[i] * ek[i];
        d = fmaxf(d, 0.0f);
        sbuf[k] = d;
        lmax = fmaxf(lmax, d);
    }
    red[tid] = lmax; __syncthreads();
    for (int s = 128; s > 0; s >>= 1) {
        if (tid < s) red[tid] = fmaxf(red[tid], red[tid + s]);
        __syncthreads();
    }
    float mx = red[0];
    __syncthreads();
    float lsum = 0.f;
    for (int k = tid; k < N_NODES; k += 256) {
        float e = expf(sbuf[k] - mx);
        sbuf[k] = e;
        lsum += e;
    }
    red[tid] = lsum; __syncthreads();
    for (int s = 128; s > 0; s >>= 1) {
        if (tid < s) red[tid] += red[tid + s];
        __syncthreads();
    }
    float tot = red[0];
    __syncthreads();

    float p[17];
#pragma unroll
    for (int i = 0; i < 17; ++i) p[i] = 0.f;
    for (int k = tid; k < N_NODES; k += 256) {
        float a = sbuf[k] / tot;
        Ady[(size_t)n * N_NODES + k] = a;
        const float* e = node_emb + k * 16;
        p[16] += a;
#pragma unroll
        for (int i = 0; i < 16; ++i) p[i] += a * e[i];
    }
    for (int e = 0; e < 17; ++e) {
        red[tid] = p[e]; __syncthreads();
        for (int s = 128; s > 0; s >>= 1) {
            if (tid < s) red[tid] += red[tid + s];
            __syncthreads();
        }
        if (tid == 0) {
            if (e < 16) node_a[n * 16 + e] = red[0];
            else rs[n] = red[0];
        }
        __syncthreads();
    }
}

// ---------------------------------------------------------------------------
// K2: node_a/rs for the predefined adjacency.
// ---------------------------------------------------------------------------
__global__ void node_rs_kernel(const float* __restrict__ A,
                               const float* __restrict__ node_emb,
                               float* __restrict__ node_a, float* __restrict__ rs)
{
    __shared__ float red[256];
    const int n = blockIdx.x;
    const int tid = threadIdx.x;
    float p[17];
#pragma unroll
    for (int i = 0; i < 17; ++i) p[i] = 0.f;
    for (int k = tid; k < N_NODES; k += 256) {
        float a = A[(size_t)n * N_NODES + k];
        const float* e = node_emb + k * 16;
        p[16] += a;
#pragma unroll
        for (int i = 0; i < 16; ++i) p[i] += a * e[i];
    }
    for (int e = 0; e < 17; ++e) {
        red[tid] = p[e]; __syncthreads();
        for (int s = 128; s > 0; s >>= 1) {
            if (tid < s) red[tid] += red[tid + s];
            __syncthreads();
        }
        if (tid == 0) {
            if (e < 16) node_a[n * 16 + e] = red[0];
            else rs[n] = red[0];
        }
        __syncthreads();
    }
}

// ---------------------------------------------------------------------------
// K3: effective weights  Wt[c][g], bW1[g]  (c = 0..2 hist, 3..34 tid/diw rows)
// ---------------------------------------------------------------------------
__global__ void prep_wt_kernel(const float* __restrict__ W_in,
                               const float* __restrict__ b_in,
                               const float* __restrict__ W,
                               float* __restrict__ Wt, float* __restrict__ bW1)
{
    int g = blockIdx.x * 256 + threadIdx.x;
    if (g >= GDIM) return;
#pragma unroll
    for (int c = 0; c < 3; ++c) {
        float s = 0.f;
        for (int m = 0; m < 64; ++m) s += W_in[c * 64 + m] * W[(size_t)m * GDIM + g];
        Wt[c * GDIM + g] = s;
    }
    float sb = 0.f;
    for (int m = 0; m < 64; ++m) sb += b_in[m] * W[(size_t)m * GDIM + g];
    bW1[g] = sb;
    for (int e = 0; e < 32; ++e)
        Wt[(3 + e) * GDIM + g] = W[(size_t)(80 + e) * GDIM + g];
}

// ---------------------------------------------------------------------------
// K4: gate constants Gc[n,g]
// ---------------------------------------------------------------------------
__global__ void gc_kernel(const float* __restrict__ node_a, const float* __restrict__ rs,
                          const float* __restrict__ W, const float* __restrict__ bW1,
                          const float* __restrict__ bg, float* __restrict__ Gc)
{
    int idx = blockIdx.x * 256 + threadIdx.x;
    if (idx >= N_NODES * GDIM) return;
    int g = idx % GDIM;
    int n = idx / GDIM;
    float s = bg[g] + rs[n] * bW1[g];
    const float* na = node_a + n * 16;
#pragma unroll
    for (int e = 0; e < 16; ++e) s += na[e] * W[(size_t)(64 + e) * GDIM + g];
    Gc[idx] = s;
}

// ---------------------------------------------------------------------------
// K5: 3-way bf16 split of stacked adjacency: Abig[m][s*2048+k], m<2048: adj,
// m>=2048: Ady.  a = a1+a2+a3 covers ~27 mantissa bits (error-free-ish).
// ---------------------------------------------------------------------------
__global__ void pack_a_kernel(const float* __restrict__ adj,
                              const float* __restrict__ Ady,
                              __hip_bfloat16* __restrict__ Abig)
{
    int flat = blockIdx.x * 256 + threadIdx.x;   // m*2048 + k, m in 0..4095
    int k = flat & 2047;
    int m = flat >> 11;
    float v = (m < 2048) ? adj[(size_t)m * 2048 + k]
                         : Ady[(size_t)(m - 2048) * 2048 + k];
    __hip_bfloat16 h1 = __float2bfloat16(v); v -= __bfloat162float(h1);
    __hip_bfloat16 h2 = __float2bfloat16(v); v -= __bfloat162float(h2);
    __hip_bfloat16 h3 = __float2bfloat16(v);
    size_t base = (size_t)m * KBIG + k;
    Abig[base]        = h1;
    Abig[base + 2048] = h2;
    Abig[base + 4096] = h3;
}

// ---------------------------------------------------------------------------
// K6: build transposed, split B chunk: XT[jl][s*2048+k] (bf16), j = j0+jl.
// Value = compact feature c of column j=(bl*35+c) at node k; pad rows zero.
// ---------------------------------------------------------------------------
__global__ void build_xt_kernel(const float* __restrict__ hist,
                                const float* __restrict__ tid_emb,
                                const float* __restrict__ diw_emb,
                                __hip_bfloat16* __restrict__ XT,
                                int j0, int njc)
{
    int flat = blockIdx.x * 256 + threadIdx.x;   // jl*2048 + k
    int k = flat & 2047;
    int jl = flat >> 11;
    if (jl >= njc) return;
    int j = j0 + jl;
    float v = 0.f;
    if (j < KC * BATCH * LSEQ) {
        int c = j % KC;
        int bl = j / KC;
        const float* h = hist + ((size_t)bl * N_NODES + k) * 3;
        if (c < 3) v = h[c];
        else if (c < 19) { int ti = (int)(h[1] * 288.0f); v = tid_emb[ti * 16 + (c - 3)]; }
        else             { int di = (int)(h[2] * 7.0f);   v = diw_emb[di * 16 + (c - 19)]; }
    }
    __hip_bfloat16 h1 = __float2bfloat16(v); v -= __bfloat162float(h1);
    __hip_bfloat16 h2 = __float2bfloat16(v); v -= __bfloat162float(h2);
    __hip_bfloat16 h3 = __float2bfloat16(v);
    size_t base = (size_t)jl * KBIG + k;
    XT[base]        = h1;
    XT[base + 2048] = h2;
    XT[base + 4096] = h3;
}

// ---------------------------------------------------------------------------
// K7: bf16 MFMA GEMM (m97 structure): C[4096][6784] += chunk of
// Abig[4096][6144] @ XT^T.  128x128 tile, BK=32, 4 waves, 4x4 16x16x32 frags,
// global_load_lds width-16 staging, fp32 accumulation.
// A and B tiles both M-major in LDS ([128 rows][32 k] bf16, row = 64 B).
// ---------------------------------------------------------------------------
__global__ __launch_bounds__(256) void gemm_bf16_kernel(const short* __restrict__ A,
                                                        const short* __restrict__ BT,
                                                        float* __restrict__ C,
                                                        int j0)
{
    __shared__ short As[128 * 32];
    __shared__ short Bs[128 * 32];
    const int tid = threadIdx.x;
    const int w = tid >> 6;          // wave 0..3
    const int l = tid & 63;
    const int wr = w >> 1;           // wave row (0..1) -> 64 output rows
    const int wc = w & 1;            // wave col (0..1) -> 64 output cols
    const int m0 = blockIdx.y * 128;
    const int jt = blockIdx.x * 128;

    // staging map: issue q in {0,1}: LDS halves; lane l covers row r, k-octet kk0
    const int r0  = ((w * 2 + 0) * 64 + l) >> 2;
    const int r1  = ((w * 2 + 1) * 64 + l) >> 2;
    const int kk0 = (l & 3) * 8;
    const size_t gA0 = (size_t)(m0 + r0) * KBIG + kk0;
    const size_t gA1 = (size_t)(m0 + r1) * KBIG + kk0;
    const size_t gB0 = (size_t)(jt + r0) * KBIG + kk0;
    const size_t gB1 = (size_t)(jt + r1) * KBIG + kk0;
    short* lA0 = &As[(w * 2 + 0) * 512];
    short* lA1 = &As[(w * 2 + 1) * 512];
    short* lB0 = &Bs[(w * 2 + 0) * 512];
    short* lB1 = &Bs[(w * 2 + 1) * 512];

    f4 acc[4][4];
#pragma unroll
    for (int i = 0; i < 4; ++i)
#pragma unroll
        for (int j = 0; j < 4; ++j)
#pragma unroll
            for (int e = 0; e < 4; ++e) acc[i][j][e] = 0.f;

    const int arow = (l & 15) * 32 + (l >> 4) * 8;   // frag base (bf16 elems)

    for (int kt = 0; kt < KBIG; kt += 32) {
        __syncthreads();                      // prior tile's ds_reads complete
        GLDS16(A  + gA0 + kt, lA0);
        GLDS16(A  + gA1 + kt, lA1);
        GLDS16(BT + gB0 + kt, lB0);
        GLDS16(BT + gB1 + kt, lB1);
        __syncthreads();                      // drains vmcnt -> tile visible
        s16x8 a[4], b[4];
#pragma unroll
        for (int mi = 0; mi < 4; ++mi)
            a[mi] = *(const s16x8*)&As[(wr * 64 + mi * 16) * 32 + arow];
#pragma unroll
        for (int ni = 0; ni < 4; ++ni)
            b[ni] = *(const s16x8*)&Bs[(wc * 64 + ni * 16) * 32 + arow];
#pragma unroll
        for (int mi = 0; mi < 4; ++mi)
#pragma unroll
            for (int ni = 0; ni < 4; ++ni)
                acc[mi][ni] = __builtin_amdgcn_mfma_f32_16x16x32_bf16(
                    a[mi], b[ni], acc[mi][ni], 0, 0, 0);
    }

    // C/D layout (verified m89): col = lane&15, row = (lane>>4)*4 + reg
    const int rbase = m0 + wr * 64 + (l >> 4) * 4;
    const int cbase = j0 + jt + wc * 64 + (l & 15);
#pragma unroll
    for (int mi = 0; mi < 4; ++mi)
#pragma unroll
        for (int ni = 0; ni < 4; ++ni)
#pragma unroll
            for (int reg = 0; reg < 4; ++reg)
                C[(size_t)(rbase + mi * 16 + reg) * NCOLS_X + cbase + ni * 16] =
                    acc[mi][ni][reg];
}

// ---------------------------------------------------------------------------
// K8: fused gates (35-term) + LSTM c-recurrence, z = layer.
// ---------------------------------------------------------------------------
__global__ __launch_bounds__(256) void lstm3_kernel(const float* __restrict__ XAall,
                                                    const float* __restrict__ Wt_pre,
                                                    const float* __restrict__ Wt_dy,
                                                    const float* __restrict__ Gc_pre,
                                                    const float* __restrict__ Gc_dy,
                                                    float* __restrict__ H)
{
    __shared__ float xa_s[32][37];
    __shared__ float c_s[32][113];
    __shared__ float t1_s[32][113];
    const int tid  = threadIdx.x;
    const int co   = tid >> 6;      // 0:i 1:f 2:g 3:o
    const int lane = tid & 63;
    const int mt   = lane & 15;
    const int nt   = lane >> 4;
    const int n0   = blockIdx.x * 32;
    const int b    = blockIdx.y;
    const int z    = blockIdx.z;

    const float* XA   = XAall + (size_t)z * N_NODES * NCOLS_X;
    const float* Wt   = z ? Wt_dy : Wt_pre;
    const float* Gc   = z ? Gc_dy : Gc_pre;
    float*       Hout = H + (size_t)z * BATCH * N_NODES * MDIM;

    for (int e = tid; e < 32 * 113; e += 256) (&c_s[0][0])[e] = 0.f;

    const float* Wc  = Wt + co * 112;
    const float* GcB = Gc + co * 112;

    float acc[8][7];

    for (int t = 0; t < LSEQ; ++t) {
        __syncthreads();
        for (int e = tid; e < 32 * KC; e += 256) {
            int n = e / KC;
            int c = e - n * KC;
            xa_s[n][c] = XA[(size_t)(n0 + n) * NCOLS_X + (b * LSEQ + t) * KC + c];
        }
        __syncthreads();
#pragma unroll
        for (int nn = 0; nn < 8; ++nn)
#pragma unroll
            for (int mm = 0; mm < 7; ++mm)
                acc[nn][mm] = GcB[(size_t)(n0 + nt * 8 + nn) * GDIM + mt + mm * 16];
#pragma unroll 5
        for (int k = 0; k < KC; ++k) {
            float w[7];
#pragma unroll
            for (int mm = 0; mm < 7; ++mm) w[mm] = Wc[k * GDIM + mt + mm * 16];
#pragma unroll
            for (int nn = 0; nn < 8; ++nn) {
                float a = xa_s[nt * 8 + nn][k];
#pragma unroll
                for (int mm = 0; mm < 7; ++mm) acc[nn][mm] = fmaf(a, w[mm], acc[nn][mm]);
            }
        }
        if (co == 0) {
#pragma unroll
            for (int nn = 0; nn < 8; ++nn)
#pragma unroll
                for (int mm = 0; mm < 7; ++mm)
                    t1_s[nt * 8 + nn][mt + mm * 16] = sigmoidf_(acc[nn][mm]);
        } else if (co == 1) {
#pragma unroll
            for (int nn = 0; nn < 8; ++nn)
#pragma unroll
                for (int mm = 0; mm < 7; ++mm)
                    c_s[nt * 8 + nn][mt + mm * 16] *= sigmoidf_(acc[nn][mm]);
        }
        __syncthreads();
        if (co == 2) {
#pragma unroll
            for (int nn = 0; nn < 8; ++nn)
#pragma unroll
                for (int mm = 0; mm < 7; ++mm)
                    c_s[nt * 8 + nn][mt + mm * 16] += tanhf(acc[nn][mm]) * t1_s[nt * 8 + nn][mt + mm * 16];
        }
        if (t == LSEQ - 1) {
            __syncthreads();
            if (co == 3) {
#pragma unroll
                for (int nn = 0; nn < 8; ++nn)
#pragma unroll
                    for (int mm = 0; mm < 7; ++mm)
                        Hout[((size_t)b * N_NODES + n0 + nt * 8 + nn) * MDIM + mt + mm * 16]
                            = sigmoidf_(acc[nn][mm]) * tanhf(c_s[nt * 8 + nn][mt + mm * 16]);
            }
        }
    }
}

// ---------------------------------------------------------------------------
// K9: fused decoder.
// ---------------------------------------------------------------------------
__global__ void decode_kernel(const float* __restrict__ H,
                              const float* __restrict__ Wdec,
                              const float* __restrict__ bdec,
                              const float* __restrict__ Wout,
                              const float* __restrict__ bout,
                              float* __restrict__ out)
{
    int g = blockIdx.x * 256 + threadIdx.x;   // g = b*2048 + n
    if (g >= BATCH * N_NODES) return;
    int b = g >> 11;
    int n = g & 2047;
    const float* h0 = H + (size_t)g * MDIM;
    const float* h1 = H + (size_t)BATCH * N_NODES * MDIM + (size_t)g * MDIM;
    float x[12];
#pragma unroll
    for (int o = 0; o < 12; ++o) x[o] = bdec[o];
    for (int m = 0; m < MDIM; ++m) {
        float a0 = h0[m], a1 = h1[m];
#pragma unroll
        for (int o = 0; o < 12; ++o)
            x[o] += a0 * Wdec[(o * 3 + 0) * MDIM + m]
                  + a1 * (Wdec[(o * 3 + 1) * MDIM + m] + Wdec[(o * 3 + 2) * MDIM + m]);
    }
#pragma unroll
    for (int p = 0; p < 12; ++p) {
        float s = bout[p];
#pragma unroll
        for (int o = 0; o < 12; ++o) s += Wout[p * 12 + o] * x[o];
        out[((size_t)b * 12 + p) * N_NODES + n] = s;
    }
}

// ---------------------------------------------------------------------------
extern "C" void kernel_launch(void* const* d_in, const int* in_sizes, int n_in,
                              void* d_out, int out_size, void* d_ws, size_t ws_size,
                              hipStream_t stream)
{
    const float* hist   = (const float*)d_in[0];
    const float* adj    = (const float*)d_in[1];
    const float* node_e = (const float*)d_in[2];
    const float* tid_e  = (const float*)d_in[3];
    const float* diw_e  = (const float*)d_in[4];
    const float* W_in   = (const float*)d_in[5];
    const float* b_in   = (const float*)d_in[6];
    const float* W_pre  = (const float*)d_in[7];
    const float* b_pre  = (const float*)d_in[8];
    const float* E_dy   = (const float*)d_in[9];
    const float* W_dy   = (const float*)d_in[10];
    const float* b_dy   = (const float*)d_in[11];
    const float* W_dec  = (const float*)d_in[12];
    const float* b_dec  = (const float*)d_in[13];
    const float* W_out  = (const float*)d_in[14];
    const float* b_out  = (const float*)d_in[15];
    float* out = (float*)d_out;

    float* ws = (float*)d_ws;
    const size_t XA_F   = (size_t)4096 * NCOLS_X;            // 27,787,264
    const size_t ABIG_F = (size_t)4096 * KBIG / 2;           // 12,582,912 (bf16)
    const size_t XT_F   = (size_t)NJ0 * KBIG / 2;            // 10,616,832 (bf16)
    const size_t GC_F   = (size_t)N_NODES * GDIM;            //    917,504

    // XA region; Ady aliases its head (dead after pack_a, before gemm writes)
    float* XA   = ws;
    float* Ady  = ws;
    float* AbigF = ws + XA_F;                 // Abig region (bf16)
    __hip_bfloat16* Abig = (__hip_bfloat16*)AbigF;
    float* Gc_pre = AbigF;                    // alias: written after gemm
    float* Gc_dy  = AbigF + GC_F;
    float* H      = AbigF + 2 * GC_F;         // [2][B][N][M] = 7,340,032
    __hip_bfloat16* XTc = (__hip_bfloat16*)(ws + XA_F + ABIG_F);
    float* tail = ws + XA_F + ABIG_F + XT_F;
    float* na_pre = tail;                     tail += (size_t)N_NODES * 16;
    float* na_dy  = tail;                     tail += (size_t)N_NODES * 16;
    float* rs_pre = tail;                     tail += N_NODES;
    float* rs_dy  = tail;                     tail += N_NODES;
    float* Wt_pre = tail;                     tail += (size_t)KC * GDIM;
    float* Wt_dy  = tail;                     tail += (size_t)KC * GDIM;
    float* bW_pre = tail;                     tail += GDIM;
    float* bW_dy  = tail;                     tail += GDIM;

    adaptive_adj_kernel<<<N_NODES, 256, 0, stream>>>(E_dy, node_e, Ady, na_dy, rs_dy);
    node_rs_kernel<<<N_NODES, 256, 0, stream>>>(adj, node_e, na_pre, rs_pre);
    prep_wt_kernel<<<2, 256, 0, stream>>>(W_in, b_in, W_pre, Wt_pre, bW_pre);
    prep_wt_kernel<<<2, 256, 0, stream>>>(W_in, b_in, W_dy, Wt_dy, bW_dy);

    // split-pack A (consumes Ady), then chunked build+GEMM over N
    pack_a_kernel<<<(4096 * 2048) / 256, 256, 0, stream>>>(adj, Ady, Abig);

    build_xt_kernel<<<(NJ0 * 2048) / 256, 256, 0, stream>>>(hist, tid_e, diw_e, XTc, 0, NJ0);
    gemm_bf16_kernel<<<dim3(NJ0 / 128, 32), 256, 0, stream>>>(
        (const short*)Abig, (const short*)XTc, XA, 0);

    build_xt_kernel<<<(NJ1 * 2048) / 256, 256, 0, stream>>>(hist, tid_e, diw_e, XTc, NJ0, NJ1);
    gemm_bf16_kernel<<<dim3(NJ1 / 128, 32), 256, 0, stream>>>(
        (const short*)Abig, (const short*)XTc, XA, NJ0);

    // gate constants (overwrite dead Abig region), then fused LSTM + decode
    gc_kernel<<<(N_NODES * GDIM + 255) / 256, 256, 0, stream>>>(na_pre, rs_pre, W_pre, bW_pre, b_pre, Gc_pre);
    gc_kernel<<<(N_NODES * GDIM + 255) / 256, 256, 0, stream>>>(na_dy, rs_dy, W_dy, bW_dy, b_dy, Gc_dy);

    lstm3_kernel<<<dim3(N_NODES / 32, BATCH, 2), 256, 0, stream>>>(
        XA, Wt_pre, Wt_dy, Gc_pre, Gc_dy, H);

    decode_kernel<<<(BATCH * N_NODES + 255) / 256, 256, 0, stream>>>(
        H, W_dec, b_dec, W_out, b_out, out);
}

// Round 7
// 753.905 us; speedup vs baseline: 3.7341x; 2.1708x over previous
//
#include <hip/hip_runtime.h>
#include <hip/hip_bf16.h>
#include <cstdint>
#include <cstddef>

typedef float f4 __attribute__((ext_vector_type(4)));
typedef short s16x8 __attribute__((ext_vector_type(8)));   // 8 bf16 in 4 VGPRs
typedef short s16x4 __attribute__((ext_vector_type(4)));

#define N_NODES 2048
#define BATCH 16
#define LSEQ 12
#define MDIM 112
#define GDIM 448                   // 4*M
#define KC 35                      // reduced contraction: 3 hist + 16 tid + 16 diw
#define NCOLS_X 6784               // KC*BATCH*LSEQ = 6720 padded to 53*128
#define KBIG 4096                  // 2 * 2048 (2-way diagonal split: A1X1 + A2X2)
#define NJ0 3456                   // chunk0 cols = 27*128
#define NJ1 3328                   // chunk1 cols = 26*128
#define KL 64                      // lstm gates contraction (35 + 3 lo + 3 lo + 18 Gc + pad)
#define WTB_SH (GDIM * KL)         // 28672 shorts = 57344 B

#define GLDS16(SRC, DST)                                                        \
    __builtin_amdgcn_global_load_lds(                                           \
        (const __attribute__((address_space(1))) void*)(SRC),                   \
        (__attribute__((address_space(3))) void*)(DST), 16, 0, 0)

#define MFMA16(ACC, AV, BV) \
    ACC = __builtin_amdgcn_mfma_f32_16x16x32_bf16(AV, BV, ACC, 0, 0, 0)

__device__ __forceinline__ short bf16hi(float v) {
    union { __hip_bfloat16 h; short s; } u;
    u.h = __float2bfloat16(v);
    return u.s;
}
__device__ __forceinline__ short bf16lo(float v) {
    union { __hip_bfloat16 h; short s; } u;
    u.h = __float2bfloat16(v);
    float r = v - __bfloat162float(u.h);
    u.h = __float2bfloat16(r);
    return u.s;
}
__device__ __forceinline__ float sigf_(float x) { return 1.0f / (1.0f + expf(-x)); }

// ---------------------------------------------------------------------------
// K1: A_dy = softmax(relu(E @ E^T), axis=1) with fused node_a/rs epilogue.
// ---------------------------------------------------------------------------
__global__ void adaptive_adj_kernel(const float* __restrict__ E,
                                    const float* __restrict__ node_emb,
                                    float* __restrict__ Ady,
                                    float* __restrict__ node_a,
                                    float* __restrict__ rs)
{
    __shared__ float sbuf[N_NODES];
    __shared__ float red[256];
    const int n = blockIdx.x;
    const int tid = threadIdx.x;
    float en[16];
#pragma unroll
    for (int i = 0; i < 16; ++i) en[i] = E[n * 16 + i];
    float lmax = -3.4e38f;
    for (int k = tid; k < N_NODES; k += 256) {
        const float* ek = E + k * 16;
        float d = 0.f;
#pragma unroll
        for (int i = 0; i < 16; ++i) d += en[i] * ek[i];
        d = fmaxf(d, 0.0f);
        sbuf[k] = d;
        lmax = fmaxf(lmax, d);
    }
    red[tid] = lmax; __syncthreads();
    for (int s = 128; s > 0; s >>= 1) {
        if (tid < s) red[tid] = fmaxf(red[tid], red[tid + s]);
        __syncthreads();
    }
    float mx = red[0];
    __syncthreads();
    float lsum = 0.f;
    for (int k = tid; k < N_NODES; k += 256) {
        float e = expf(sbuf[k] - mx);
        sbuf[k] = e;
        lsum += e;
    }
    red[tid] = lsum; __syncthreads();
    for (int s = 128; s > 0; s >>= 1) {
        if (tid < s) red[tid] += red[tid + s];
        __syncthreads();
    }
    float tot = red[0];
    __syncthreads();

    float p[17];
#pragma unroll
    for (int i = 0; i < 17; ++i) p[i] = 0.f;
    for (int k = tid; k < N_NODES; k += 256) {
        float a = sbuf[k] / tot;
        Ady[(size_t)n * N_NODES + k] = a;
        const float* e = node_emb + k * 16;
        p[16] += a;
#pragma unroll
        for (int i = 0; i < 16; ++i) p[i] += a * e[i];
    }
    for (int e = 0; e < 17; ++e) {
        red[tid] = p[e]; __syncthreads();
        for (int s = 128; s > 0; s >>= 1) {
            if (tid < s) red[tid] += red[tid + s];
            __syncthreads();
        }
        if (tid == 0) {
            if (e < 16) node_a[n * 16 + e] = red[0];
            else rs[n] = red[0];
        }
        __syncthreads();
    }
}

// ---------------------------------------------------------------------------
// K2: node_a/rs for the predefined adjacency.
// ---------------------------------------------------------------------------
__global__ void node_rs_kernel(const float* __restrict__ A,
                               const float* __restrict__ node_emb,
                               float* __restrict__ node_a, float* __restrict__ rs)
{
    __shared__ float red[256];
    const int n = blockIdx.x;
    const int tid = threadIdx.x;
    float p[17];
#pragma unroll
    for (int i = 0; i < 17; ++i) p[i] = 0.f;
    for (int k = tid; k < N_NODES; k += 256) {
        float a = A[(size_t)n * N_NODES + k];
        const float* e = node_emb + k * 16;
        p[16] += a;
#pragma unroll
        for (int i = 0; i < 16; ++i) p[i] += a * e[i];
    }
    for (int e = 0; e < 17; ++e) {
        red[tid] = p[e]; __syncthreads();
        for (int s = 128; s > 0; s >>= 1) {
            if (tid < s) red[tid] += red[tid + s];
            __syncthreads();
        }
        if (tid == 0) {
            if (e < 16) node_a[n * 16 + e] = red[0];
            else rs[n] = red[0];
        }
        __syncthreads();
    }
}

// ---------------------------------------------------------------------------
// K3: effective weights  Wt[c][g], bW1[g]  (c = 0..2 hist, 3..34 tid/diw rows)
// ---------------------------------------------------------------------------
__global__ void prep_wt_kernel(const float* __restrict__ W_in,
                               const float* __restrict__ b_in,
                               const float* __restrict__ W,
                               float* __restrict__ Wt, float* __restrict__ bW1)
{
    int g = blockIdx.x * 256 + threadIdx.x;
    if (g >= GDIM) return;
#pragma unroll
    for (int c = 0; c < 3; ++c) {
        float s = 0.f;
        for (int m = 0; m < 64; ++m) s += W_in[c * 64 + m] * W[(size_t)m * GDIM + g];
        Wt[c * GDIM + g] = s;
    }
    float sb = 0.f;
    for (int m = 0; m < 64; ++m) sb += b_in[m] * W[(size_t)m * GDIM + g];
    bW1[g] = sb;
    for (int e = 0; e < 32; ++e)
        Wt[(3 + e) * GDIM + g] = W[(size_t)(80 + e) * GDIM + g];
}

// ---------------------------------------------------------------------------
// K4: pack gate-weight B operand for the MFMA lstm, PRE-SWIZZLED bf16.
// Row r = (mi*4+co)*16 + gc  <->  g = co*112 + mi*16 + gc.  K-positions p:
//  p<35: hi(Wt[p])     35..37: hi(Wt[p-35])   38..40: lo(Wt[p-38])
//  41: hi(bg)  42: hi(bW1)  43..58: hi(W[64+e])  59: lo(bg)  60: lo(bW1)
// Store at byte addr a=r*128+p*2 swizzled by a ^= ((r&7)<<4)  (pure XOR,
// bijective within each 128-B row).
// ---------------------------------------------------------------------------
__global__ void wtb_pack_kernel(const float* __restrict__ Wt,
                                const float* __restrict__ bW1,
                                const float* __restrict__ bg,
                                const float* __restrict__ Worig,
                                short* __restrict__ outp)
{
    int idx = blockIdx.x * 256 + threadIdx.x;      // r*64 + p
    if (idx >= GDIM * KL) return;
    int p = idx & 63;
    int r = idx >> 6;
    int tile = r >> 4, gc = r & 15;
    int mi = tile >> 2, co = tile & 3;
    int g = co * 112 + mi * 16 + gc;
    float v = 0.f; bool lo = false; bool zero = false;
    if (p < 35)        v = Wt[p * GDIM + g];
    else if (p < 38)   v = Wt[(p - 35) * GDIM + g];
    else if (p < 41) { v = Wt[(p - 38) * GDIM + g]; lo = true; }
    else if (p == 41)  v = bg[g];
    else if (p == 42)  v = bW1[g];
    else if (p < 59)   v = Worig[(size_t)(64 + p - 43) * GDIM + g];
    else if (p == 59) { v = bg[g]; lo = true; }
    else if (p == 60) { v = bW1[g]; lo = true; }
    else zero = true;
    short s = zero ? (short)0 : (lo ? bf16lo(v) : bf16hi(v));
    int a = r * 128 + p * 2;
    int asw = a ^ (((a >> 7) & 7) << 4);
    outp[asw >> 1] = s;
}

// ---------------------------------------------------------------------------
// K5: 2-way bf16 diagonal split of stacked adjacency (m<2048 adj, else Ady).
// ---------------------------------------------------------------------------
__global__ void pack_a_kernel(const float* __restrict__ adj,
                              const float* __restrict__ Ady,
                              __hip_bfloat16* __restrict__ Abig)
{
    int flat = blockIdx.x * 256 + threadIdx.x;   // m*2048 + k, m in 0..4095
    int k = flat & 2047;
    int m = flat >> 11;
    float v = (m < 2048) ? adj[(size_t)m * 2048 + k]
                         : Ady[(size_t)(m - 2048) * 2048 + k];
    __hip_bfloat16 h1 = __float2bfloat16(v); v -= __bfloat162float(h1);
    __hip_bfloat16 h2 = __float2bfloat16(v);
    size_t base = (size_t)m * KBIG + k;
    Abig[base]        = h1;
    Abig[base + 2048] = h2;
}

// ---------------------------------------------------------------------------
// K6: build transposed, 2-way-split B chunk: XT[jl][s*2048+k] (bf16).
// ---------------------------------------------------------------------------
__global__ void build_xt_kernel(const float* __restrict__ hist,
                                const float* __restrict__ tid_emb,
                                const float* __restrict__ diw_emb,
                                __hip_bfloat16* __restrict__ XT,
                                int j0, int njc)
{
    int flat = blockIdx.x * 256 + threadIdx.x;   // jl*2048 + k
    int k = flat & 2047;
    int jl = flat >> 11;
    if (jl >= njc) return;
    int j = j0 + jl;
    float v = 0.f;
    if (j < KC * BATCH * LSEQ) {
        int c = j % KC;
        int bl = j / KC;
        const float* h = hist + ((size_t)bl * N_NODES + k) * 3;
        if (c < 3) v = h[c];
        else if (c < 19) { int ti = (int)(h[1] * 288.0f); v = tid_emb[ti * 16 + (c - 3)]; }
        else             { int di = (int)(h[2] * 7.0f);   v = diw_emb[di * 16 + (c - 19)]; }
    }
    __hip_bfloat16 h1 = __float2bfloat16(v); v -= __bfloat162float(h1);
    __hip_bfloat16 h2 = __float2bfloat16(v);
    size_t base = (size_t)jl * KBIG + k;
    XT[base]        = h1;
    XT[base + 2048] = h2;
}

// ---------------------------------------------------------------------------
// K7: bf16 MFMA GEMM (m97 structure): C[4096][6784] = Abig[4096][4096] @ XT^T.
// 128x128 tile, BK=32, 4 waves, 4x4 16x16x32 frags, global_load_lds staging.
// ---------------------------------------------------------------------------
__global__ __launch_bounds__(256) void gemm_bf16_kernel(const short* __restrict__ A,
                                                        const short* __restrict__ BT,
                                                        float* __restrict__ C,
                                                        int j0)
{
    __shared__ short As[128 * 32];
    __shared__ short Bs[128 * 32];
    const int tid = threadIdx.x;
    const int w = tid >> 6;          // wave 0..3
    const int l = tid & 63;
    const int wr = w >> 1;
    const int wc = w & 1;
    const int m0 = blockIdx.y * 128;
    const int jt = blockIdx.x * 128;

    const int r0  = ((w * 2 + 0) * 64 + l) >> 2;
    const int r1  = ((w * 2 + 1) * 64 + l) >> 2;
    const int kk0 = (l & 3) * 8;
    const size_t gA0 = (size_t)(m0 + r0) * KBIG + kk0;
    const size_t gA1 = (size_t)(m0 + r1) * KBIG + kk0;
    const size_t gB0 = (size_t)(jt + r0) * KBIG + kk0;
    const size_t gB1 = (size_t)(jt + r1) * KBIG + kk0;
    short* lA0 = &As[(w * 2 + 0) * 512];
    short* lA1 = &As[(w * 2 + 1) * 512];
    short* lB0 = &Bs[(w * 2 + 0) * 512];
    short* lB1 = &Bs[(w * 2 + 1) * 512];

    f4 acc[4][4];
#pragma unroll
    for (int i = 0; i < 4; ++i)
#pragma unroll
        for (int j = 0; j < 4; ++j)
#pragma unroll
            for (int e = 0; e < 4; ++e) acc[i][j][e] = 0.f;

    const int arow = (l & 15) * 32 + (l >> 4) * 8;

    for (int kt = 0; kt < KBIG; kt += 32) {
        __syncthreads();
        GLDS16(A  + gA0 + kt, lA0);
        GLDS16(A  + gA1 + kt, lA1);
        GLDS16(BT + gB0 + kt, lB0);
        GLDS16(BT + gB1 + kt, lB1);
        __syncthreads();
        s16x8 a[4], b[4];
#pragma unroll
        for (int mi = 0; mi < 4; ++mi)
            a[mi] = *(const s16x8*)&As[(wr * 64 + mi * 16) * 32 + arow];
#pragma unroll
        for (int ni = 0; ni < 4; ++ni)
            b[ni] = *(const s16x8*)&Bs[(wc * 64 + ni * 16) * 32 + arow];
#pragma unroll
        for (int mi = 0; mi < 4; ++mi)
#pragma unroll
            for (int ni = 0; ni < 4; ++ni)
                MFMA16(acc[mi][ni], a[mi], b[ni]);
    }

    const int rbase = m0 + wr * 64 + (l >> 4) * 4;
    const int cbase = j0 + jt + wc * 64 + (l & 15);
#pragma unroll
    for (int mi = 0; mi < 4; ++mi)
#pragma unroll
        for (int ni = 0; ni < 4; ++ni)
#pragma unroll
            for (int reg = 0; reg < 4; ++reg)
                C[(size_t)(rbase + mi * 16 + reg) * NCOLS_X + cbase + ni * 16] =
                    acc[mi][ni][reg];
}

// ---------------------------------------------------------------------------
// K8: fused MFMA gates + LSTM c-recurrence.  Block = (64 nodes, b, z).
// WtB (448x64 bf16, XOR-swizzled) resident in LDS; Xa (64x64 bf16) staged
// per t; Gc folded into the contraction via 18 extra K-rows; c in registers;
// o-gate MFMA only at t=11.  4 waves x 16 nodes each.
// FIX (r6->r7): Xa staging offset is (chunk ^ swz) — XOR of the chunk offset,
// not XOR of the row base followed by ADD (which carried past bit 6 and
// corrupted neighboring rows -> uninit LDS reads -> NaN).
// ---------------------------------------------------------------------------
__global__ __launch_bounds__(256, 2) void lstm4_kernel(
    const float* __restrict__ XA,
    const short* __restrict__ WtBg,            // [2][WTB_SH] pre-swizzled
    const float* __restrict__ na_pre, const float* __restrict__ na_dy,
    const float* __restrict__ rs_pre, const float* __restrict__ rs_dy,
    float* __restrict__ H)
{
    __shared__ short sWtb[WTB_SH];             // 57344 B
    __shared__ short sXa[64 * KL];             //  8192 B
    const int tid = threadIdx.x;
    const int w = tid >> 6, l = tid & 63;
    const int n0 = blockIdx.x * 64;
    const int b  = blockIdx.y;
    const int z  = blockIdx.z;
    const float* na = z ? na_dy : na_pre;
    const float* rs = z ? rs_dy : rs_pre;

    // stage WtB via global_load_lds (pre-swizzled source, linear dest)
    {
        const char* gW = (const char*)(WtBg + (size_t)z * WTB_SH);
        char* lW = (char*)sWtb;
        for (int it = 0; it < 14; ++it) {
            int base = (it * 4 + w) * 64;      // 16B-chunk index, wave-uniform
            GLDS16(gW + (size_t)(base + l) * 16, lW + base * 16);
        }
    }

    // staging identities (each wave stages p-quarter pp=w for all 64 rows)
    const int srow = l;
    const int pp = w;
    const float* xarow = XA + (size_t)(z * 2048 + n0 + srow) * NCOLS_X;
    const float* narow = na + (size_t)(n0 + srow) * 16;
    const float rsv = rs[n0 + srow];
    char* wrow = (char*)sXa + srow * 128;      // row base (bits >= 7 only)
    const int wswz = (srow & 7) << 4;          // swizzle key (bits 4..6)

    // compute identities
    const int lm = l & 15;
    const int sm = (l & 7) << 4;
    const int kof0 = ((l >> 4) * 16) ^ sm;           // ks=0 swizzled k-offset
    const int kof1 = (64 + (l >> 4) * 16) ^ sm;      // ks=1
    const int an = w * 16 + lm;                      // A-frag row (node in block)
    const char* xab = (const char*)sXa;
    const char* wtbb = (const char*)sWtb;
    float* Hout = H + (size_t)z * BATCH * N_NODES * MDIM;

    float cc[7][4];
#pragma unroll
    for (int mi = 0; mi < 7; ++mi)
#pragma unroll
        for (int q = 0; q < 4; ++q) cc[mi][q] = 0.f;

    for (int t = 0; t < LSEQ; ++t) {
        __syncthreads();     // prior reads of sXa done; first iter drains WtB DMA
        {
            const int col0 = (b * LSEQ + t) * KC;
            short v[16];
            if (pp < 2) {
#pragma unroll
                for (int j = 0; j < 16; ++j) v[j] = bf16hi(xarow[col0 + pp * 16 + j]);
            } else if (pp == 2) {
                v[0] = bf16hi(xarow[col0 + 32]);
                v[1] = bf16hi(xarow[col0 + 33]);
                v[2] = bf16hi(xarow[col0 + 34]);
                v[3] = bf16lo(xarow[col0 + 0]);
                v[4] = bf16lo(xarow[col0 + 1]);
                v[5] = bf16lo(xarow[col0 + 2]);
                v[6] = bf16hi(xarow[col0 + 0]);
                v[7] = bf16hi(xarow[col0 + 1]);
                v[8] = bf16hi(xarow[col0 + 2]);
                v[9]  = bf16hi(1.0f);
                v[10] = bf16hi(rsv);
#pragma unroll
                for (int j = 11; j < 16; ++j) v[j] = bf16hi(narow[j - 11]);
            } else {
#pragma unroll
                for (int j = 0; j < 11; ++j) v[j] = bf16hi(narow[5 + j]);
                v[11] = bf16hi(1.0f);
                v[12] = bf16hi(rsv);
                v[13] = 0; v[14] = 0; v[15] = 0;
            }
#pragma unroll
            for (int q = 0; q < 4; ++q) {
                s16x4 sv = { v[q * 4], v[q * 4 + 1], v[q * 4 + 2], v[q * 4 + 3] };
                *(s16x4*)(wrow + ((pp * 32 + q * 8) ^ wswz)) = sv;   // pure XOR: bijective
            }
        }
        __syncthreads();

        s16x8 a0 = *(const s16x8*)(xab + an * 128 + kof0);
        s16x8 a1 = *(const s16x8*)(xab + an * 128 + kof1);
#pragma unroll
        for (int mi = 0; mi < 7; ++mi) {
            const char* bb = wtbb + (mi * 64 + lm) * 128;   // co=0 row; co step = +2048B
            f4 gi = {0.f, 0.f, 0.f, 0.f};
            f4 gf = gi, gg = gi;
            MFMA16(gi, a0, *(const s16x8*)(bb + kof0));
            MFMA16(gi, a1, *(const s16x8*)(bb + kof1));
            MFMA16(gf, a0, *(const s16x8*)(bb + 2048 + kof0));
            MFMA16(gf, a1, *(const s16x8*)(bb + 2048 + kof1));
            MFMA16(gg, a0, *(const s16x8*)(bb + 4096 + kof0));
            MFMA16(gg, a1, *(const s16x8*)(bb + 4096 + kof1));
#pragma unroll
            for (int q = 0; q < 4; ++q) {
                float si = sigf_(gi[q]);
                float sf = sigf_(gf[q]);
                float tg = tanhf(gg[q]);
                cc[mi][q] = sf * cc[mi][q] + si * tg;
            }
            if (t == LSEQ - 1) {
                f4 go = {0.f, 0.f, 0.f, 0.f};
                MFMA16(go, a0, *(const s16x8*)(bb + 6144 + kof0));
                MFMA16(go, a1, *(const s16x8*)(bb + 6144 + kof1));
#pragma unroll
                for (int q = 0; q < 4; ++q) {
                    float h = sigf_(go[q]) * tanhf(cc[mi][q]);
                    Hout[((size_t)b * N_NODES + n0 + w * 16 + (l >> 4) * 4 + q) * MDIM
                         + mi * 16 + lm] = h;
                }
            }
        }
    }
}

// ---------------------------------------------------------------------------
// K9: fused decoder (layers 1 and 2 identical -> weight folding).
// ---------------------------------------------------------------------------
__global__ void decode_kernel(const float* __restrict__ H,
                              const float* __restrict__ Wdec,
                              const float* __restrict__ bdec,
                              const float* __restrict__ Wout,
                              const float* __restrict__ bout,
                              float* __restrict__ out)
{
    int g = blockIdx.x * 256 + threadIdx.x;   // g = b*2048 + n
    if (g >= BATCH * N_NODES) return;
    int b = g >> 11;
    int n = g & 2047;
    const float* h0 = H + (size_t)g * MDIM;
    const float* h1 = H + (size_t)BATCH * N_NODES * MDIM + (size_t)g * MDIM;
    float x[12];
#pragma unroll
    for (int o = 0; o < 12; ++o) x[o] = bdec[o];
    for (int m = 0; m < MDIM; ++m) {
        float a0 = h0[m], a1 = h1[m];
#pragma unroll
        for (int o = 0; o < 12; ++o)
            x[o] += a0 * Wdec[(o * 3 + 0) * MDIM + m]
                  + a1 * (Wdec[(o * 3 + 1) * MDIM + m] + Wdec[(o * 3 + 2) * MDIM + m]);
    }
#pragma unroll
    for (int p = 0; p < 12; ++p) {
        float s = bout[p];
#pragma unroll
        for (int o = 0; o < 12; ++o) s += Wout[p * 12 + o] * x[o];
        out[((size_t)b * 12 + p) * N_NODES + n] = s;
    }
}

// ---------------------------------------------------------------------------
extern "C" void kernel_launch(void* const* d_in, const int* in_sizes, int n_in,
                              void* d_out, int out_size, void* d_ws, size_t ws_size,
                              hipStream_t stream)
{
    const float* hist   = (const float*)d_in[0];
    const float* adj    = (const float*)d_in[1];
    const float* node_e = (const float*)d_in[2];
    const float* tid_e  = (const float*)d_in[3];
    const float* diw_e  = (const float*)d_in[4];
    const float* W_in   = (const float*)d_in[5];
    const float* b_in   = (const float*)d_in[6];
    const float* W_pre  = (const float*)d_in[7];
    const float* b_pre  = (const float*)d_in[8];
    const float* E_dy   = (const float*)d_in[9];
    const float* W_dy   = (const float*)d_in[10];
    const float* b_dy   = (const float*)d_in[11];
    const float* W_dec  = (const float*)d_in[12];
    const float* b_dec  = (const float*)d_in[13];
    const float* W_out  = (const float*)d_in[14];
    const float* b_out  = (const float*)d_in[15];
    float* out = (float*)d_out;

    float* ws = (float*)d_ws;
    const size_t XA_F   = (size_t)4096 * NCOLS_X;            // 27,787,264 floats
    const size_t ABIG_F = (size_t)4096 * KBIG / 2;           //  8,388,608 float-equiv
    const size_t XT_F   = (size_t)NJ0 * KBIG / 2;            //  7,077,888 float-equiv

    float* XA    = ws;                        // [4096][NCOLS_X]
    float* Ady   = ws;                        // aliases XA head; dead before gemm
    float* AbigF = ws + XA_F;
    __hip_bfloat16* Abig = (__hip_bfloat16*)AbigF;
    float* H     = AbigF;                     // aliases Abig; written after gemms
    __hip_bfloat16* XTc = (__hip_bfloat16*)(ws + XA_F + ABIG_F);
    float* tail = ws + XA_F + ABIG_F + XT_F;
    float* na_pre = tail;                     tail += (size_t)N_NODES * 16;
    float* na_dy  = tail;                     tail += (size_t)N_NODES * 16;
    float* rs_pre = tail;                     tail += N_NODES;
    float* rs_dy  = tail;                     tail += N_NODES;
    float* Wt_pre = tail;                     tail += (size_t)KC * GDIM;
    float* Wt_dy  = tail;                     tail += (size_t)KC * GDIM;
    float* bW_pre = tail;                     tail += GDIM;
    float* bW_dy  = tail;                     tail += GDIM;
    short* WtBg   = (short*)tail;             // 2 * WTB_SH shorts

    adaptive_adj_kernel<<<N_NODES, 256, 0, stream>>>(E_dy, node_e, Ady, na_dy, rs_dy);
    node_rs_kernel<<<N_NODES, 256, 0, stream>>>(adj, node_e, na_pre, rs_pre);
    prep_wt_kernel<<<2, 256, 0, stream>>>(W_in, b_in, W_pre, Wt_pre, bW_pre);
    prep_wt_kernel<<<2, 256, 0, stream>>>(W_in, b_in, W_dy, Wt_dy, bW_dy);
    wtb_pack_kernel<<<(GDIM * KL + 255) / 256, 256, 0, stream>>>(
        Wt_pre, bW_pre, b_pre, W_pre, WtBg);
    wtb_pack_kernel<<<(GDIM * KL + 255) / 256, 256, 0, stream>>>(
        Wt_dy, bW_dy, b_dy, W_dy, WtBg + WTB_SH);

    // split-pack A (consumes Ady), then chunked build+GEMM over N
    pack_a_kernel<<<(4096 * 2048) / 256, 256, 0, stream>>>(adj, Ady, Abig);

    build_xt_kernel<<<(NJ0 * 2048) / 256, 256, 0, stream>>>(hist, tid_e, diw_e, XTc, 0, NJ0);
    gemm_bf16_kernel<<<dim3(NJ0 / 128, 32), 256, 0, stream>>>(
        (const short*)Abig, (const short*)XTc, XA, 0);

    build_xt_kernel<<<(NJ1 * 2048) / 256, 256, 0, stream>>>(hist, tid_e, diw_e, XTc, NJ0, NJ1);
    gemm_bf16_kernel<<<dim3(NJ1 / 128, 32), 256, 0, stream>>>(
        (const short*)Abig, (const short*)XTc, XA, NJ0);

    // fused MFMA gates + recurrence (H overwrites dead Abig region)
    lstm4_kernel<<<dim3(N_NODES / 64, BATCH, 2), 256, 0, stream>>>(
        XA, WtBg, na_pre, na_dy, rs_pre, rs_dy, H);

    decode_kernel<<<(BATCH * N_NODES + 255) / 256, 256, 0, stream>>>(
        H, W_dec, b_dec, W_out, b_out, out);
}

// Round 8
// 525.478 us; speedup vs baseline: 5.3573x; 1.4347x over previous
//
#include <hip/hip_runtime.h>
#include <hip/hip_bf16.h>
#include <cstdint>
#include <cstddef>

typedef float f4 __attribute__((ext_vector_type(4)));
typedef short s16x8 __attribute__((ext_vector_type(8)));   // 8 bf16 in 4 VGPRs
typedef short s16x4 __attribute__((ext_vector_type(4)));

#define N_NODES 2048
#define BATCH 16
#define LSEQ 12
#define MDIM 112
#define GDIM 448                   // 4*M
#define KC 35                      // reduced contraction: 3 hist + 16 tid + 16 diw
#define NCOLS_X 6784               // KC*BATCH*LSEQ = 6720 padded to 53*128
#define KBIG 2048                  // hi-only bf16 (split dropped: see R8 theory)
#define KL 64                      // lstm gates contraction (35 + 3 lo + 3 lo + 18 Gc + pad)
#define WTB_SH (GDIM * KL)         // 28672 shorts = 57344 B

#define GLDS16(SRC, DST)                                                        \
    __builtin_amdgcn_global_load_lds(                                           \
        (const __attribute__((address_space(1))) void*)(SRC),                   \
        (__attribute__((address_space(3))) void*)(DST), 16, 0, 0)

#define MFMA16(ACC, AV, BV) \
    ACC = __builtin_amdgcn_mfma_f32_16x16x32_bf16(AV, BV, ACC, 0, 0, 0)

__device__ __forceinline__ short bf16hi(float v) {
    union { __hip_bfloat16 h; short s; } u;
    u.h = __float2bfloat16(v);
    return u.s;
}
__device__ __forceinline__ short bf16lo(float v) {
    union { __hip_bfloat16 h; short s; } u;
    u.h = __float2bfloat16(v);
    float r = v - __bfloat162float(u.h);
    u.h = __float2bfloat16(r);
    return u.s;
}
// fast activations: ~2ulp __expf; gate error budget dominated by bf16 (4.5e-6)
__device__ __forceinline__ float sigf_(float x)  { return 1.0f / (1.0f + __expf(-x)); }
__device__ __forceinline__ float tanhf_(float x) { return 1.0f - 2.0f / (1.0f + __expf(2.0f * x)); }

// ---------------------------------------------------------------------------
// K1: A_dy = softmax(relu(E @ E^T), axis=1) with fused node_a/rs epilogue.
// ---------------------------------------------------------------------------
__global__ void adaptive_adj_kernel(const float* __restrict__ E,
                                    const float* __restrict__ node_emb,
                                    float* __restrict__ Ady,
                                    float* __restrict__ node_a,
                                    float* __restrict__ rs)
{
    __shared__ float sbuf[N_NODES];
    __shared__ float red[256];
    const int n = blockIdx.x;
    const int tid = threadIdx.x;
    float en[16];
#pragma unroll
    for (int i = 0; i < 16; ++i) en[i] = E[n * 16 + i];
    float lmax = -3.4e38f;
    for (int k = tid; k < N_NODES; k += 256) {
        const float* ek = E + k * 16;
        float d = 0.f;
#pragma unroll
        for (int i = 0; i < 16; ++i) d += en[i] * ek[i];
        d = fmaxf(d, 0.0f);
        sbuf[k] = d;
        lmax = fmaxf(lmax, d);
    }
    red[tid] = lmax; __syncthreads();
    for (int s = 128; s > 0; s >>= 1) {
        if (tid < s) red[tid] = fmaxf(red[tid], red[tid + s]);
        __syncthreads();
    }
    float mx = red[0];
    __syncthreads();
    float lsum = 0.f;
    for (int k = tid; k < N_NODES; k += 256) {
        float e = expf(sbuf[k] - mx);
        sbuf[k] = e;
        lsum += e;
    }
    red[tid] = lsum; __syncthreads();
    for (int s = 128; s > 0; s >>= 1) {
        if (tid < s) red[tid] += red[tid + s];
        __syncthreads();
    }
    float tot = red[0];
    __syncthreads();

    float p[17];
#pragma unroll
    for (int i = 0; i < 17; ++i) p[i] = 0.f;
    for (int k = tid; k < N_NODES; k += 256) {
        float a = sbuf[k] / tot;
        Ady[(size_t)n * N_NODES + k] = a;
        const float* e = node_emb + k * 16;
        p[16] += a;
#pragma unroll
        for (int i = 0; i < 16; ++i) p[i] += a * e[i];
    }
    for (int e = 0; e < 17; ++e) {
        red[tid] = p[e]; __syncthreads();
        for (int s = 128; s > 0; s >>= 1) {
            if (tid < s) red[tid] += red[tid + s];
            __syncthreads();
        }
        if (tid == 0) {
            if (e < 16) node_a[n * 16 + e] = red[0];
            else rs[n] = red[0];
        }
        __syncthreads();
    }
}

// ---------------------------------------------------------------------------
// K2: node_a/rs for the predefined adjacency.
// ---------------------------------------------------------------------------
__global__ void node_rs_kernel(const float* __restrict__ A,
                               const float* __restrict__ node_emb,
                               float* __restrict__ node_a, float* __restrict__ rs)
{
    __shared__ float red[256];
    const int n = blockIdx.x;
    const int tid = threadIdx.x;
    float p[17];
#pragma unroll
    for (int i = 0; i < 17; ++i) p[i] = 0.f;
    for (int k = tid; k < N_NODES; k += 256) {
        float a = A[(size_t)n * N_NODES + k];
        const float* e = node_emb + k * 16;
        p[16] += a;
#pragma unroll
        for (int i = 0; i < 16; ++i) p[i] += a * e[i];
    }
    for (int e = 0; e < 17; ++e) {
        red[tid] = p[e]; __syncthreads();
        for (int s = 128; s > 0; s >>= 1) {
            if (tid < s) red[tid] += red[tid + s];
            __syncthreads();
        }
        if (tid == 0) {
            if (e < 16) node_a[n * 16 + e] = red[0];
            else rs[n] = red[0];
        }
        __syncthreads();
    }
}

// ---------------------------------------------------------------------------
// K3: effective weights  Wt[c][g], bW1[g]  (c = 0..2 hist, 3..34 tid/diw rows)
// ---------------------------------------------------------------------------
__global__ void prep_wt_kernel(const float* __restrict__ W_in,
                               const float* __restrict__ b_in,
                               const float* __restrict__ W,
                               float* __restrict__ Wt, float* __restrict__ bW1)
{
    int g = blockIdx.x * 256 + threadIdx.x;
    if (g >= GDIM) return;
#pragma unroll
    for (int c = 0; c < 3; ++c) {
        float s = 0.f;
        for (int m = 0; m < 64; ++m) s += W_in[c * 64 + m] * W[(size_t)m * GDIM + g];
        Wt[c * GDIM + g] = s;
    }
    float sb = 0.f;
    for (int m = 0; m < 64; ++m) sb += b_in[m] * W[(size_t)m * GDIM + g];
    bW1[g] = sb;
    for (int e = 0; e < 32; ++e)
        Wt[(3 + e) * GDIM + g] = W[(size_t)(80 + e) * GDIM + g];
}

// ---------------------------------------------------------------------------
// K4: pack gate-weight B operand for the MFMA lstm, PRE-SWIZZLED bf16.
// Row r = (mi*4+co)*16 + gc  <->  g = co*112 + mi*16 + gc.  K-positions p:
//  p<35: hi(Wt[p])     35..37: hi(Wt[p-35])   38..40: lo(Wt[p-38])
//  41: hi(bg)  42: hi(bW1)  43..58: hi(W[64+e])  59: lo(bg)  60: lo(bW1)
// Store at byte addr a=r*128+p*2 swizzled by a ^= ((r&7)<<4)  (pure XOR).
// ---------------------------------------------------------------------------
__global__ void wtb_pack_kernel(const float* __restrict__ Wt,
                                const float* __restrict__ bW1,
                                const float* __restrict__ bg,
                                const float* __restrict__ Worig,
                                short* __restrict__ outp)
{
    int idx = blockIdx.x * 256 + threadIdx.x;      // r*64 + p
    if (idx >= GDIM * KL) return;
    int p = idx & 63;
    int r = idx >> 6;
    int tile = r >> 4, gc = r & 15;
    int mi = tile >> 2, co = tile & 3;
    int g = co * 112 + mi * 16 + gc;
    float v = 0.f; bool lo = false; bool zero = false;
    if (p < 35)        v = Wt[p * GDIM + g];
    else if (p < 38)   v = Wt[(p - 35) * GDIM + g];
    else if (p < 41) { v = Wt[(p - 38) * GDIM + g]; lo = true; }
    else if (p == 41)  v = bg[g];
    else if (p == 42)  v = bW1[g];
    else if (p < 59)   v = Worig[(size_t)(64 + p - 43) * GDIM + g];
    else if (p == 59) { v = bg[g]; lo = true; }
    else if (p == 60) { v = bW1[g]; lo = true; }
    else zero = true;
    short s = zero ? (short)0 : (lo ? bf16lo(v) : bf16hi(v));
    int a = r * 128 + p * 2;
    int asw = a ^ (((a >> 7) & 7) << 4);
    outp[asw >> 1] = s;
}

// ---------------------------------------------------------------------------
// K5: hi-only bf16 pack of stacked adjacency (m<2048 adj, else Ady).
// ---------------------------------------------------------------------------
__global__ void pack_a_kernel(const float* __restrict__ adj,
                              const float* __restrict__ Ady,
                              __hip_bfloat16* __restrict__ Abig)
{
    int flat = blockIdx.x * 256 + threadIdx.x;   // m*2048 + k, m in 0..4095
    int k = flat & 2047;
    int m = flat >> 11;
    float v = (m < 2048) ? adj[(size_t)m * 2048 + k]
                         : Ady[(size_t)(m - 2048) * 2048 + k];
    Abig[(size_t)m * KBIG + k] = __float2bfloat16(v);
}

// ---------------------------------------------------------------------------
// K6: build transposed hi-only B: XT[jl][k] (bf16), full N.
// ---------------------------------------------------------------------------
__global__ void build_xt_kernel(const float* __restrict__ hist,
                                const float* __restrict__ tid_emb,
                                const float* __restrict__ diw_emb,
                                __hip_bfloat16* __restrict__ XT)
{
    int flat = blockIdx.x * 256 + threadIdx.x;   // jl*2048 + k
    int k = flat & 2047;
    int jl = flat >> 11;
    if (jl >= NCOLS_X) return;
    float v = 0.f;
    if (jl < KC * BATCH * LSEQ) {
        int c = jl % KC;
        int bl = jl / KC;
        const float* h = hist + ((size_t)bl * N_NODES + k) * 3;
        if (c < 3) v = h[c];
        else if (c < 19) { int ti = (int)(h[1] * 288.0f); v = tid_emb[ti * 16 + (c - 3)]; }
        else             { int di = (int)(h[2] * 7.0f);   v = diw_emb[di * 16 + (c - 19)]; }
    }
    XT[(size_t)jl * KBIG + k] = __float2bfloat16(v);
}

// ---------------------------------------------------------------------------
// K7: bf16 MFMA GEMM: C[4096][6784] = Abig[4096][2048] @ XT^T, one dispatch.
// 128x128 tile, BK=32, 4 waves, 4x4 16x16x32 frags, global_load_lds staging.
// XCD row-band swizzle: 1696 blocks = 8 XCDs x 212 = 8 x (4 rows x 53 cols);
// each XCD's A-band (4 x 0.5 MB) fits its private L2.
// ---------------------------------------------------------------------------
__global__ __launch_bounds__(256) void gemm_bf16_kernel(const short* __restrict__ A,
                                                        const short* __restrict__ BT,
                                                        float* __restrict__ C)
{
    __shared__ short As[128 * 32];
    __shared__ short Bs[128 * 32];
    const int tid = threadIdx.x;
    const int w = tid >> 6;          // wave 0..3
    const int l = tid & 63;
    const int wr = w >> 1;
    const int wc = w & 1;

    const int bid = blockIdx.y * 53 + blockIdx.x;       // physical dispatch id
    const int sid = (bid & 7) * 212 + (bid >> 3);       // XCD-contiguous id
    const int m0 = (sid / 53) * 128;
    const int jt = (sid % 53) * 128;

    const int r0  = ((w * 2 + 0) * 64 + l) >> 2;
    const int r1  = ((w * 2 + 1) * 64 + l) >> 2;
    const int kk0 = (l & 3) * 8;
    const size_t gA0 = (size_t)(m0 + r0) * KBIG + kk0;
    const size_t gA1 = (size_t)(m0 + r1) * KBIG + kk0;
    const size_t gB0 = (size_t)(jt + r0) * KBIG + kk0;
    const size_t gB1 = (size_t)(jt + r1) * KBIG + kk0;
    short* lA0 = &As[(w * 2 + 0) * 512];
    short* lA1 = &As[(w * 2 + 1) * 512];
    short* lB0 = &Bs[(w * 2 + 0) * 512];
    short* lB1 = &Bs[(w * 2 + 1) * 512];

    f4 acc[4][4];
#pragma unroll
    for (int i = 0; i < 4; ++i)
#pragma unroll
        for (int j = 0; j < 4; ++j)
#pragma unroll
            for (int e = 0; e < 4; ++e) acc[i][j][e] = 0.f;

    const int arow = (l & 15) * 32 + (l >> 4) * 8;

    for (int kt = 0; kt < KBIG; kt += 32) {
        __syncthreads();
        GLDS16(A  + gA0 + kt, lA0);
        GLDS16(A  + gA1 + kt, lA1);
        GLDS16(BT + gB0 + kt, lB0);
        GLDS16(BT + gB1 + kt, lB1);
        __syncthreads();
        s16x8 a[4], b[4];
#pragma unroll
        for (int mi = 0; mi < 4; ++mi)
            a[mi] = *(const s16x8*)&As[(wr * 64 + mi * 16) * 32 + arow];
#pragma unroll
        for (int ni = 0; ni < 4; ++ni)
            b[ni] = *(const s16x8*)&Bs[(wc * 64 + ni * 16) * 32 + arow];
#pragma unroll
        for (int mi = 0; mi < 4; ++mi)
#pragma unroll
            for (int ni = 0; ni < 4; ++ni)
                MFMA16(acc[mi][ni], a[mi], b[ni]);
    }

    const int rbase = m0 + wr * 64 + (l >> 4) * 4;
    const int cbase = jt + wc * 64 + (l & 15);
#pragma unroll
    for (int mi = 0; mi < 4; ++mi)
#pragma unroll
        for (int ni = 0; ni < 4; ++ni)
#pragma unroll
            for (int reg = 0; reg < 4; ++reg)
                C[(size_t)(rbase + mi * 16 + reg) * NCOLS_X + cbase + ni * 16] =
                    acc[mi][ni][reg];
}

// ---------------------------------------------------------------------------
// K8: fused MFMA gates + LSTM c-recurrence.  Block = (64 nodes, b, z).
// WtB (448x64 bf16, XOR-swizzled) resident in LDS; Xa (64x64 bf16) staged
// per t; Gc folded into the contraction via 18 extra K-rows; c in registers;
// o-gate MFMA only at t=11.  Fast __expf activations (R8).
// ---------------------------------------------------------------------------
__global__ __launch_bounds__(256, 2) void lstm4_kernel(
    const float* __restrict__ XA,
    const short* __restrict__ WtBg,            // [2][WTB_SH] pre-swizzled
    const float* __restrict__ na_pre, const float* __restrict__ na_dy,
    const float* __restrict__ rs_pre, const float* __restrict__ rs_dy,
    float* __restrict__ H)
{
    __shared__ short sWtb[WTB_SH];             // 57344 B
    __shared__ short sXa[64 * KL];             //  8192 B
    const int tid = threadIdx.x;
    const int w = tid >> 6, l = tid & 63;
    const int n0 = blockIdx.x * 64;
    const int b  = blockIdx.y;
    const int z  = blockIdx.z;
    const float* na = z ? na_dy : na_pre;
    const float* rs = z ? rs_dy : rs_pre;

    // stage WtB via global_load_lds (pre-swizzled source, linear dest)
    {
        const char* gW = (const char*)(WtBg + (size_t)z * WTB_SH);
        char* lW = (char*)sWtb;
        for (int it = 0; it < 14; ++it) {
            int base = (it * 4 + w) * 64;      // 16B-chunk index, wave-uniform
            GLDS16(gW + (size_t)(base + l) * 16, lW + base * 16);
        }
    }

    // staging identities (each wave stages p-quarter pp=w for all 64 rows)
    const int srow = l;
    const int pp = w;
    const float* xarow = XA + (size_t)(z * 2048 + n0 + srow) * NCOLS_X;
    const float* narow = na + (size_t)(n0 + srow) * 16;
    const float rsv = rs[n0 + srow];
    char* wrow = (char*)sXa + srow * 128;      // row base (bits >= 7 only)
    const int wswz = (srow & 7) << 4;          // swizzle key (bits 4..6)

    // compute identities
    const int lm = l & 15;
    const int sm = (l & 7) << 4;
    const int kof0 = ((l >> 4) * 16) ^ sm;           // ks=0 swizzled k-offset
    const int kof1 = (64 + (l >> 4) * 16) ^ sm;      // ks=1
    const int an = w * 16 + lm;                      // A-frag row (node in block)
    const char* xab = (const char*)sXa;
    const char* wtbb = (const char*)sWtb;
    float* Hout = H + (size_t)z * BATCH * N_NODES * MDIM;

    float cc[7][4];
#pragma unroll
    for (int mi = 0; mi < 7; ++mi)
#pragma unroll
        for (int q = 0; q < 4; ++q) cc[mi][q] = 0.f;

    for (int t = 0; t < LSEQ; ++t) {
        __syncthreads();     // prior reads of sXa done; first iter drains WtB DMA
        {
            const int col0 = (b * LSEQ + t) * KC;
            short v[16];
            if (pp < 2) {
#pragma unroll
                for (int j = 0; j < 16; ++j) v[j] = bf16hi(xarow[col0 + pp * 16 + j]);
            } else if (pp == 2) {
                v[0] = bf16hi(xarow[col0 + 32]);
                v[1] = bf16hi(xarow[col0 + 33]);
                v[2] = bf16hi(xarow[col0 + 34]);
                v[3] = bf16lo(xarow[col0 + 0]);
                v[4] = bf16lo(xarow[col0 + 1]);
                v[5] = bf16lo(xarow[col0 + 2]);
                v[6] = bf16hi(xarow[col0 + 0]);
                v[7] = bf16hi(xarow[col0 + 1]);
                v[8] = bf16hi(xarow[col0 + 2]);
                v[9]  = bf16hi(1.0f);
                v[10] = bf16hi(rsv);
#pragma unroll
                for (int j = 11; j < 16; ++j) v[j] = bf16hi(narow[j - 11]);
            } else {
#pragma unroll
                for (int j = 0; j < 11; ++j) v[j] = bf16hi(narow[5 + j]);
                v[11] = bf16hi(1.0f);
                v[12] = bf16hi(rsv);
                v[13] = 0; v[14] = 0; v[15] = 0;
            }
#pragma unroll
            for (int q = 0; q < 4; ++q) {
                s16x4 sv = { v[q * 4], v[q * 4 + 1], v[q * 4 + 2], v[q * 4 + 3] };
                *(s16x4*)(wrow + ((pp * 32 + q * 8) ^ wswz)) = sv;   // pure XOR: bijective
            }
        }
        __syncthreads();

        s16x8 a0 = *(const s16x8*)(xab + an * 128 + kof0);
        s16x8 a1 = *(const s16x8*)(xab + an * 128 + kof1);
#pragma unroll
        for (int mi = 0; mi < 7; ++mi) {
            const char* bb = wtbb + (mi * 64 + lm) * 128;   // co=0 row; co step = +2048B
            f4 gi = {0.f, 0.f, 0.f, 0.f};
            f4 gf = gi, gg = gi;
            MFMA16(gi, a0, *(const s16x8*)(bb + kof0));
            MFMA16(gi, a1, *(const s16x8*)(bb + kof1));
            MFMA16(gf, a0, *(const s16x8*)(bb + 2048 + kof0));
            MFMA16(gf, a1, *(const s16x8*)(bb + 2048 + kof1));
            MFMA16(gg, a0, *(const s16x8*)(bb + 4096 + kof0));
            MFMA16(gg, a1, *(const s16x8*)(bb + 4096 + kof1));
#pragma unroll
            for (int q = 0; q < 4; ++q) {
                float si = sigf_(gi[q]);
                float sf = sigf_(gf[q]);
                float tg = tanhf_(gg[q]);
                cc[mi][q] = sf * cc[mi][q] + si * tg;
            }
            if (t == LSEQ - 1) {
                f4 go = {0.f, 0.f, 0.f, 0.f};
                MFMA16(go, a0, *(const s16x8*)(bb + 6144 + kof0));
                MFMA16(go, a1, *(const s16x8*)(bb + 6144 + kof1));
#pragma unroll
                for (int q = 0; q < 4; ++q) {
                    float h = sigf_(go[q]) * tanhf_(cc[mi][q]);
                    Hout[((size_t)b * N_NODES + n0 + w * 16 + (l >> 4) * 4 + q) * MDIM
                         + mi * 16 + lm] = h;
                }
            }
        }
    }
}

// ---------------------------------------------------------------------------
// K9: fused decoder (layers 1 and 2 identical -> weight folding).
// ---------------------------------------------------------------------------
__global__ void decode_kernel(const float* __restrict__ H,
                              const float* __restrict__ Wdec,
                              const float* __restrict__ bdec,
                              const float* __restrict__ Wout,
                              const float* __restrict__ bout,
                              float* __restrict__ out)
{
    int g = blockIdx.x * 256 + threadIdx.x;   // g = b*2048 + n
    if (g >= BATCH * N_NODES) return;
    int b = g >> 11;
    int n = g & 2047;
    const float* h0 = H + (size_t)g * MDIM;
    const float* h1 = H + (size_t)BATCH * N_NODES * MDIM + (size_t)g * MDIM;
    float x[12];
#pragma unroll
    for (int o = 0; o < 12; ++o) x[o] = bdec[o];
    for (int m = 0; m < MDIM; ++m) {
        float a0 = h0[m], a1 = h1[m];
#pragma unroll
        for (int o = 0; o < 12; ++o)
            x[o] += a0 * Wdec[(o * 3 + 0) * MDIM + m]
                  + a1 * (Wdec[(o * 3 + 1) * MDIM + m] + Wdec[(o * 3 + 2) * MDIM + m]);
    }
#pragma unroll
    for (int p = 0; p < 12; ++p) {
        float s = bout[p];
#pragma unroll
        for (int o = 0; o < 12; ++o) s += Wout[p * 12 + o] * x[o];
        out[((size_t)b * 12 + p) * N_NODES + n] = s;
    }
}

// ---------------------------------------------------------------------------
extern "C" void kernel_launch(void* const* d_in, const int* in_sizes, int n_in,
                              void* d_out, int out_size, void* d_ws, size_t ws_size,
                              hipStream_t stream)
{
    const float* hist   = (const float*)d_in[0];
    const float* adj    = (const float*)d_in[1];
    const float* node_e = (const float*)d_in[2];
    const float* tid_e  = (const float*)d_in[3];
    const float* diw_e  = (const float*)d_in[4];
    const float* W_in   = (const float*)d_in[5];
    const float* b_in   = (const float*)d_in[6];
    const float* W_pre  = (const float*)d_in[7];
    const float* b_pre  = (const float*)d_in[8];
    const float* E_dy   = (const float*)d_in[9];
    const float* W_dy   = (const float*)d_in[10];
    const float* b_dy   = (const float*)d_in[11];
    const float* W_dec  = (const float*)d_in[12];
    const float* b_dec  = (const float*)d_in[13];
    const float* W_out  = (const float*)d_in[14];
    const float* b_out  = (const float*)d_in[15];
    float* out = (float*)d_out;

    float* ws = (float*)d_ws;
    const size_t XA_F   = (size_t)4096 * NCOLS_X;            // 27,787,264 floats
    const size_t ABIG_F = (size_t)4096 * KBIG / 2;           //  4,194,304 float-equiv
    const size_t XT_F   = (size_t)NCOLS_X * KBIG / 2;        //  6,946,816 float-equiv

    float* XA    = ws;                        // [4096][NCOLS_X]
    float* Ady   = ws;                        // aliases XA head; dead before gemm
    float* AbigF = ws + XA_F;
    __hip_bfloat16* Abig = (__hip_bfloat16*)AbigF;
    float* H     = AbigF;                     // aliases Abig+XT (dead after gemm); 7.34M < 11.1M
    __hip_bfloat16* XTc = (__hip_bfloat16*)(ws + XA_F + ABIG_F);
    float* tail = ws + XA_F + ABIG_F + XT_F;
    float* na_pre = tail;                     tail += (size_t)N_NODES * 16;
    float* na_dy  = tail;                     tail += (size_t)N_NODES * 16;
    float* rs_pre = tail;                     tail += N_NODES;
    float* rs_dy  = tail;                     tail += N_NODES;
    float* Wt_pre = tail;                     tail += (size_t)KC * GDIM;
    float* Wt_dy  = tail;                     tail += (size_t)KC * GDIM;
    float* bW_pre = tail;                     tail += GDIM;
    float* bW_dy  = tail;                     tail += GDIM;
    short* WtBg   = (short*)tail;             // 2 * WTB_SH shorts

    adaptive_adj_kernel<<<N_NODES, 256, 0, stream>>>(E_dy, node_e, Ady, na_dy, rs_dy);
    node_rs_kernel<<<N_NODES, 256, 0, stream>>>(adj, node_e, na_pre, rs_pre);
    prep_wt_kernel<<<2, 256, 0, stream>>>(W_in, b_in, W_pre, Wt_pre, bW_pre);
    prep_wt_kernel<<<2, 256, 0, stream>>>(W_in, b_in, W_dy, Wt_dy, bW_dy);
    wtb_pack_kernel<<<(GDIM * KL + 255) / 256, 256, 0, stream>>>(
        Wt_pre, bW_pre, b_pre, W_pre, WtBg);
    wtb_pack_kernel<<<(GDIM * KL + 255) / 256, 256, 0, stream>>>(
        Wt_dy, bW_dy, b_dy, W_dy, WtBg + WTB_SH);

    // hi-only pack (consumes Ady), full-N build, ONE GEMM dispatch
    pack_a_kernel<<<(4096 * 2048) / 256, 256, 0, stream>>>(adj, Ady, Abig);
    build_xt_kernel<<<(NCOLS_X * 2048) / 256, 256, 0, stream>>>(hist, tid_e, diw_e, XTc);
    gemm_bf16_kernel<<<dim3(53, 32), 256, 0, stream>>>(
        (const short*)Abig, (const short*)XTc, XA);

    // fused MFMA gates + recurrence (H overwrites dead Abig/XT region)
    lstm4_kernel<<<dim3(N_NODES / 64, BATCH, 2), 256, 0, stream>>>(
        XA, WtBg, na_pre, na_dy, rs_pre, rs_dy, H);

    decode_kernel<<<(BATCH * N_NODES + 255) / 256, 256, 0, stream>>>(
        H, W_dec, b_dec, W_out, b_out, out);
}

// Round 9
// 437.211 us; speedup vs baseline: 6.4388x; 1.2019x over previous
//
#include <hip/hip_runtime.h>
#include <hip/hip_bf16.h>
#include <cstdint>
#include <cstddef>

typedef float f4 __attribute__((ext_vector_type(4)));
typedef short s16x8 __attribute__((ext_vector_type(8)));   // 8 bf16 in 4 VGPRs
typedef short s16x4 __attribute__((ext_vector_type(4)));

#define N_NODES 2048
#define BATCH 16
#define LSEQ 12
#define MDIM 112
#define GDIM 448                   // 4*M
#define KC 35                      // reduced contraction: 3 hist + 16 tid + 16 diw
#define NCOLS_X 6784               // KC*BATCH*LSEQ = 6720 padded to 53*128
#define KBIG 2048                  // hi-only bf16
#define KL 64                      // lstm gates contraction (35 + 3 lo + 3 lo + 18 Gc + pad)
#define WTB_SH (GDIM * KL)         // 28672 shorts = 57344 B

#define GLDS16(SRC, DST)                                                        \
    __builtin_amdgcn_global_load_lds(                                           \
        (const __attribute__((address_space(1))) void*)(SRC),                   \
        (__attribute__((address_space(3))) void*)(DST), 16, 0, 0)

#define MFMA16(ACC, AV, BV) \
    ACC = __builtin_amdgcn_mfma_f32_16x16x32_bf16(AV, BV, ACC, 0, 0, 0)

__device__ __forceinline__ short bf16hi(float v) {
    union { __hip_bfloat16 h; short s; } u;
    u.h = __float2bfloat16(v);
    return u.s;
}
__device__ __forceinline__ short bf16lo(float v) {
    union { __hip_bfloat16 h; short s; } u;
    u.h = __float2bfloat16(v);
    float r = v - __bfloat162float(u.h);
    u.h = __float2bfloat16(r);
    return u.s;
}
// fast activations: ~2ulp __expf; gate error budget dominated by bf16 (4.5e-6)
__device__ __forceinline__ float sigf_(float x)  { return 1.0f / (1.0f + __expf(-x)); }
__device__ __forceinline__ float tanhf_(float x) { return 1.0f - 2.0f / (1.0f + __expf(2.0f * x)); }

__device__ __forceinline__ float wave_sum(float v) {
#pragma unroll
    for (int off = 32; off > 0; off >>= 1) v += __shfl_down(v, off);
    return v;
}

// ---------------------------------------------------------------------------
// K1: A_dy = softmax(relu(E @ E^T), axis=1) with fused node_a/rs epilogue
// (epilogue via wave shuffle-reduce: 1 barrier instead of 136).
// ---------------------------------------------------------------------------
__global__ void adaptive_adj_kernel(const float* __restrict__ E,
                                    const float* __restrict__ node_emb,
                                    float* __restrict__ Ady,
                                    float* __restrict__ node_a,
                                    float* __restrict__ rs)
{
    __shared__ float sbuf[N_NODES];
    __shared__ float red[256];
    __shared__ float part[17][4];
    const int n = blockIdx.x;
    const int tid = threadIdx.x;
    float en[16];
#pragma unroll
    for (int i = 0; i < 16; ++i) en[i] = E[n * 16 + i];
    float lmax = -3.4e38f;
    for (int k = tid; k < N_NODES; k += 256) {
        const float* ek = E + k * 16;
        float d = 0.f;
#pragma unroll
        for (int i = 0; i < 16; ++i) d += en[i] * ek[i];
        d = fmaxf(d, 0.0f);
        sbuf[k] = d;
        lmax = fmaxf(lmax, d);
    }
    red[tid] = lmax; __syncthreads();
    for (int s = 128; s > 0; s >>= 1) {
        if (tid < s) red[tid] = fmaxf(red[tid], red[tid + s]);
        __syncthreads();
    }
    float mx = red[0];
    __syncthreads();
    float lsum = 0.f;
    for (int k = tid; k < N_NODES; k += 256) {
        float e = expf(sbuf[k] - mx);
        sbuf[k] = e;
        lsum += e;
    }
    red[tid] = lsum; __syncthreads();
    for (int s = 128; s > 0; s >>= 1) {
        if (tid < s) red[tid] += red[tid + s];
        __syncthreads();
    }
    float tot = red[0];
    __syncthreads();

    float p[17];
#pragma unroll
    for (int i = 0; i < 17; ++i) p[i] = 0.f;
    for (int k = tid; k < N_NODES; k += 256) {
        float a = sbuf[k] / tot;
        Ady[(size_t)n * N_NODES + k] = a;
        const float* e = node_emb + k * 16;
        p[16] += a;
#pragma unroll
        for (int i = 0; i < 16; ++i) p[i] += a * e[i];
    }
#pragma unroll
    for (int e = 0; e < 17; ++e) {
        float v = wave_sum(p[e]);
        if ((tid & 63) == 0) part[e][tid >> 6] = v;
    }
    __syncthreads();
    if (tid < 17) {
        float s = part[tid][0] + part[tid][1] + part[tid][2] + part[tid][3];
        if (tid < 16) node_a[n * 16 + tid] = s;
        else rs[n] = s;
    }
}

// ---------------------------------------------------------------------------
// K2: node_a/rs for the predefined adjacency (shuffle-reduce epilogue).
// ---------------------------------------------------------------------------
__global__ void node_rs_kernel(const float* __restrict__ A,
                               const float* __restrict__ node_emb,
                               float* __restrict__ node_a, float* __restrict__ rs)
{
    __shared__ float part[17][4];
    const int n = blockIdx.x;
    const int tid = threadIdx.x;
    float p[17];
#pragma unroll
    for (int i = 0; i < 17; ++i) p[i] = 0.f;
    for (int k = tid; k < N_NODES; k += 256) {
        float a = A[(size_t)n * N_NODES + k];
        const float* e = node_emb + k * 16;
        p[16] += a;
#pragma unroll
        for (int i = 0; i < 16; ++i) p[i] += a * e[i];
    }
#pragma unroll
    for (int e = 0; e < 17; ++e) {
        float v = wave_sum(p[e]);
        if ((tid & 63) == 0) part[e][tid >> 6] = v;
    }
    __syncthreads();
    if (tid < 17) {
        float s = part[tid][0] + part[tid][1] + part[tid][2] + part[tid][3];
        if (tid < 16) node_a[n * 16 + tid] = s;
        else rs[n] = s;
    }
}

// ---------------------------------------------------------------------------
// K3: effective weights  Wt[c][g], bW1[g]  (c = 0..2 hist, 3..34 tid/diw rows)
// ---------------------------------------------------------------------------
__global__ void prep_wt_kernel(const float* __restrict__ W_in,
                               const float* __restrict__ b_in,
                               const float* __restrict__ W,
                               float* __restrict__ Wt, float* __restrict__ bW1)
{
    int g = blockIdx.x * 256 + threadIdx.x;
    if (g >= GDIM) return;
#pragma unroll
    for (int c = 0; c < 3; ++c) {
        float s = 0.f;
        for (int m = 0; m < 64; ++m) s += W_in[c * 64 + m] * W[(size_t)m * GDIM + g];
        Wt[c * GDIM + g] = s;
    }
    float sb = 0.f;
    for (int m = 0; m < 64; ++m) sb += b_in[m] * W[(size_t)m * GDIM + g];
    bW1[g] = sb;
    for (int e = 0; e < 32; ++e)
        Wt[(3 + e) * GDIM + g] = W[(size_t)(80 + e) * GDIM + g];
}

// ---------------------------------------------------------------------------
// K4: pack gate-weight B operand for the MFMA lstm, PRE-SWIZZLED bf16.
// ---------------------------------------------------------------------------
__global__ void wtb_pack_kernel(const float* __restrict__ Wt,
                                const float* __restrict__ bW1,
                                const float* __restrict__ bg,
                                const float* __restrict__ Worig,
                                short* __restrict__ outp)
{
    int idx = blockIdx.x * 256 + threadIdx.x;      // r*64 + p
    if (idx >= GDIM * KL) return;
    int p = idx & 63;
    int r = idx >> 6;
    int tile = r >> 4, gc = r & 15;
    int mi = tile >> 2, co = tile & 3;
    int g = co * 112 + mi * 16 + gc;
    float v = 0.f; bool lo = false; bool zero = false;
    if (p < 35)        v = Wt[p * GDIM + g];
    else if (p < 38)   v = Wt[(p - 35) * GDIM + g];
    else if (p < 41) { v = Wt[(p - 38) * GDIM + g]; lo = true; }
    else if (p == 41)  v = bg[g];
    else if (p == 42)  v = bW1[g];
    else if (p < 59)   v = Worig[(size_t)(64 + p - 43) * GDIM + g];
    else if (p == 59) { v = bg[g]; lo = true; }
    else if (p == 60) { v = bW1[g]; lo = true; }
    else zero = true;
    short s = zero ? (short)0 : (lo ? bf16lo(v) : bf16hi(v));
    int a = r * 128 + p * 2;
    int asw = a ^ (((a >> 7) & 7) << 4);
    outp[asw >> 1] = s;
}

// ---------------------------------------------------------------------------
// K5: hi-only bf16 pack of stacked adjacency, 4-wide vectorized.
// ---------------------------------------------------------------------------
__global__ void pack_a_kernel(const float* __restrict__ adj,
                              const float* __restrict__ Ady,
                              __hip_bfloat16* __restrict__ Abig)
{
    int idx = blockIdx.x * 256 + threadIdx.x;    // each handles 4 consecutive k
    int e0 = idx << 2;
    int k = e0 & 2047;
    int m = e0 >> 11;
    const float* src = (m < 2048) ? adj + ((size_t)m * 2048 + k)
                                  : Ady + ((size_t)(m - 2048) * 2048 + k);
    f4 v = *(const f4*)src;
    s16x4 o = { bf16hi(v[0]), bf16hi(v[1]), bf16hi(v[2]), bf16hi(v[3]) };
    *(s16x4*)((short*)Abig + (size_t)m * KBIG + k) = o;
}

// ---------------------------------------------------------------------------
// K6: build transposed hi-only B: XT[jl][k] (bf16), 4-wide per thread.
// ---------------------------------------------------------------------------
__global__ void build_xt_kernel(const float* __restrict__ hist,
                                const float* __restrict__ tid_emb,
                                const float* __restrict__ diw_emb,
                                __hip_bfloat16* __restrict__ XT)
{
    int idx = blockIdx.x * 256 + threadIdx.x;    // < NCOLS_X*2048/4
    int e0 = idx << 2;
    int k0 = e0 & 2047;
    int jl = e0 >> 11;
    s16x4 o = {0, 0, 0, 0};
    if (jl < KC * BATCH * LSEQ) {
        int c = jl % KC;
        int bl = jl / KC;
#pragma unroll
        for (int i = 0; i < 4; ++i) {
            const float* h = hist + ((size_t)(bl * N_NODES + k0 + i)) * 3;
            float v;
            if (c < 3) v = h[c];
            else if (c < 19) { int ti = (int)(h[1] * 288.0f); v = tid_emb[ti * 16 + (c - 3)]; }
            else             { int di = (int)(h[2] * 7.0f);   v = diw_emb[di * 16 + (c - 19)]; }
            o[i] = bf16hi(v);
        }
    }
    *(s16x4*)((short*)XT + (size_t)jl * KBIG + k0) = o;
}

// ---------------------------------------------------------------------------
// K7: bf16 MFMA GEMM: C[4096][6784] = Abig[4096][2048] @ XT^T.
// 256x128 tile, BK=32, 512 threads (8 waves, 4x2), 4x4 16x16x32 frags/wave,
// global_load_lds staging.  Column-major XCD swizzle: 848 = 8 x 106; each
// XCD owns ~6.6 B column-panels (3.3 MB, L2-resident) and streams A.
// ---------------------------------------------------------------------------
__global__ __launch_bounds__(512, 4) void gemm_bf16_kernel(const short* __restrict__ A,
                                                           const short* __restrict__ BT,
                                                           float* __restrict__ C)
{
    __shared__ short As[256 * 32];     // 16 KB
    __shared__ short Bs[128 * 32];     //  8 KB
    const int tid = threadIdx.x;
    const int w = tid >> 6;            // wave 0..7
    const int l = tid & 63;
    const int wr = w >> 1;             // 0..3 -> 64-row band
    const int wc = w & 1;              // 0..1 -> 64-col band

    const int bid = blockIdx.y * 53 + blockIdx.x;        // 0..847
    const int sid = (bid & 7) * 106 + (bid >> 3);        // XCD-contiguous
    const int col = sid >> 4;                            // 0..52 (column-major)
    const int row = sid & 15;                            // 0..15
    const int m0 = row * 256;
    const int jt = col * 128;

    // staging maps (3 x GLDS16 per thread per K-step)
    const int arow0 = tid >> 2;                 // A chunk 0: rows 0..127
    const int akc   = (tid & 3) * 8;            // k-octet (shorts)
    const size_t gA0 = (size_t)(m0 + arow0) * KBIG + akc;
    const size_t gA1 = (size_t)(m0 + 128 + arow0) * KBIG + akc;
    const size_t gB0 = (size_t)(jt + arow0) * KBIG + akc;
    char* lA0 = (char*)As + tid * 16;
    char* lA1 = (char*)As + 8192 + tid * 16;
    char* lB0 = (char*)Bs + tid * 16;

    f4 acc[4][4];
#pragma unroll
    for (int i = 0; i < 4; ++i)
#pragma unroll
        for (int j = 0; j < 4; ++j)
#pragma unroll
            for (int e = 0; e < 4; ++e) acc[i][j][e] = 0.f;

    const int fkof = (l >> 4) * 8;              // k-offset within frag (shorts)

    for (int kt = 0; kt < KBIG; kt += 32) {
        __syncthreads();
        GLDS16(A  + gA0 + kt, lA0);
        GLDS16(A  + gA1 + kt, lA1);
        GLDS16(BT + gB0 + kt, lB0);
        __syncthreads();
        s16x8 a[4], b[4];
#pragma unroll
        for (int mi = 0; mi < 4; ++mi)
            a[mi] = *(const s16x8*)&As[(wr * 64 + mi * 16 + (l & 15)) * 32 + fkof];
#pragma unroll
        for (int ni = 0; ni < 4; ++ni)
            b[ni] = *(const s16x8*)&Bs[(wc * 64 + ni * 16 + (l & 15)) * 32 + fkof];
#pragma unroll
        for (int mi = 0; mi < 4; ++mi)
#pragma unroll
            for (int ni = 0; ni < 4; ++ni)
                MFMA16(acc[mi][ni], a[mi], b[ni]);
    }

    const int rbase = m0 + wr * 64 + (l >> 4) * 4;
    const int cbase = jt + wc * 64 + (l & 15);
#pragma unroll
    for (int mi = 0; mi < 4; ++mi)
#pragma unroll
        for (int ni = 0; ni < 4; ++ni)
#pragma unroll
            for (int reg = 0; reg < 4; ++reg)
                C[(size_t)(rbase + mi * 16 + reg) * NCOLS_X + cbase + ni * 16] =
                    acc[mi][ni][reg];
}

// ---------------------------------------------------------------------------
// K8: fused MFMA gates + LSTM c-recurrence (unchanged from round 8).
// ---------------------------------------------------------------------------
__global__ __launch_bounds__(256, 2) void lstm4_kernel(
    const float* __restrict__ XA,
    const short* __restrict__ WtBg,            // [2][WTB_SH] pre-swizzled
    const float* __restrict__ na_pre, const float* __restrict__ na_dy,
    const float* __restrict__ rs_pre, const float* __restrict__ rs_dy,
    float* __restrict__ H)
{
    __shared__ short sWtb[WTB_SH];             // 57344 B
    __shared__ short sXa[64 * KL];             //  8192 B
    const int tid = threadIdx.x;
    const int w = tid >> 6, l = tid & 63;
    const int n0 = blockIdx.x * 64;
    const int b  = blockIdx.y;
    const int z  = blockIdx.z;
    const float* na = z ? na_dy : na_pre;
    const float* rs = z ? rs_dy : rs_pre;

    {
        const char* gW = (const char*)(WtBg + (size_t)z * WTB_SH);
        char* lW = (char*)sWtb;
        for (int it = 0; it < 14; ++it) {
            int base = (it * 4 + w) * 64;
            GLDS16(gW + (size_t)(base + l) * 16, lW + base * 16);
        }
    }

    const int srow = l;
    const int pp = w;
    const float* xarow = XA + (size_t)(z * 2048 + n0 + srow) * NCOLS_X;
    const float* narow = na + (size_t)(n0 + srow) * 16;
    const float rsv = rs[n0 + srow];
    char* wrow = (char*)sXa + srow * 128;
    const int wswz = (srow & 7) << 4;

    const int lm = l & 15;
    const int sm = (l & 7) << 4;
    const int kof0 = ((l >> 4) * 16) ^ sm;
    const int kof1 = (64 + (l >> 4) * 16) ^ sm;
    const int an = w * 16 + lm;
    const char* xab = (const char*)sXa;
    const char* wtbb = (const char*)sWtb;
    float* Hout = H + (size_t)z * BATCH * N_NODES * MDIM;

    float cc[7][4];
#pragma unroll
    for (int mi = 0; mi < 7; ++mi)
#pragma unroll
        for (int q = 0; q < 4; ++q) cc[mi][q] = 0.f;

    for (int t = 0; t < LSEQ; ++t) {
        __syncthreads();
        {
            const int col0 = (b * LSEQ + t) * KC;
            short v[16];
            if (pp < 2) {
#pragma unroll
                for (int j = 0; j < 16; ++j) v[j] = bf16hi(xarow[col0 + pp * 16 + j]);
            } else if (pp == 2) {
                v[0] = bf16hi(xarow[col0 + 32]);
                v[1] = bf16hi(xarow[col0 + 33]);
                v[2] = bf16hi(xarow[col0 + 34]);
                v[3] = bf16lo(xarow[col0 + 0]);
                v[4] = bf16lo(xarow[col0 + 1]);
                v[5] = bf16lo(xarow[col0 + 2]);
                v[6] = bf16hi(xarow[col0 + 0]);
                v[7] = bf16hi(xarow[col0 + 1]);
                v[8] = bf16hi(xarow[col0 + 2]);
                v[9]  = bf16hi(1.0f);
                v[10] = bf16hi(rsv);
#pragma unroll
                for (int j = 11; j < 16; ++j) v[j] = bf16hi(narow[j - 11]);
            } else {
#pragma unroll
                for (int j = 0; j < 11; ++j) v[j] = bf16hi(narow[5 + j]);
                v[11] = bf16hi(1.0f);
                v[12] = bf16hi(rsv);
                v[13] = 0; v[14] = 0; v[15] = 0;
            }
#pragma unroll
            for (int q = 0; q < 4; ++q) {
                s16x4 sv = { v[q * 4], v[q * 4 + 1], v[q * 4 + 2], v[q * 4 + 3] };
                *(s16x4*)(wrow + ((pp * 32 + q * 8) ^ wswz)) = sv;
            }
        }
        __syncthreads();

        s16x8 a0 = *(const s16x8*)(xab + an * 128 + kof0);
        s16x8 a1 = *(const s16x8*)(xab + an * 128 + kof1);
#pragma unroll
        for (int mi = 0; mi < 7; ++mi) {
            const char* bb = wtbb + (mi * 64 + lm) * 128;
            f4 gi = {0.f, 0.f, 0.f, 0.f};
            f4 gf = gi, gg = gi;
            MFMA16(gi, a0, *(const s16x8*)(bb + kof0));
            MFMA16(gi, a1, *(const s16x8*)(bb + kof1));
            MFMA16(gf, a0, *(const s16x8*)(bb + 2048 + kof0));
            MFMA16(gf, a1, *(const s16x8*)(bb + 2048 + kof1));
            MFMA16(gg, a0, *(const s16x8*)(bb + 4096 + kof0));
            MFMA16(gg, a1, *(const s16x8*)(bb + 4096 + kof1));
#pragma unroll
            for (int q = 0; q < 4; ++q) {
                float si = sigf_(gi[q]);
                float sf = sigf_(gf[q]);
                float tg = tanhf_(gg[q]);
                cc[mi][q] = sf * cc[mi][q] + si * tg;
            }
            if (t == LSEQ - 1) {
                f4 go = {0.f, 0.f, 0.f, 0.f};
                MFMA16(go, a0, *(const s16x8*)(bb + 6144 + kof0));
                MFMA16(go, a1, *(const s16x8*)(bb + 6144 + kof1));
#pragma unroll
                for (int q = 0; q < 4; ++q) {
                    float h = sigf_(go[q]) * tanhf_(cc[mi][q]);
                    Hout[((size_t)b * N_NODES + n0 + w * 16 + (l >> 4) * 4 + q) * MDIM
                         + mi * 16 + lm] = h;
                }
            }
        }
    }
}

// ---------------------------------------------------------------------------
// K9: fused decoder, f4-vectorized H loads.
// ---------------------------------------------------------------------------
__global__ void decode_kernel(const float* __restrict__ H,
                              const float* __restrict__ Wdec,
                              const float* __restrict__ bdec,
                              const float* __restrict__ Wout,
                              const float* __restrict__ bout,
                              float* __restrict__ out)
{
    int g = blockIdx.x * 256 + threadIdx.x;   // g = b*2048 + n
    if (g >= BATCH * N_NODES) return;
    int b = g >> 11;
    int n = g & 2047;
    const f4* h0 = (const f4*)(H + (size_t)g * MDIM);
    const f4* h1 = (const f4*)(H + (size_t)BATCH * N_NODES * MDIM + (size_t)g * MDIM);
    float x[12];
#pragma unroll
    for (int o = 0; o < 12; ++o) x[o] = bdec[o];
    for (int mq = 0; mq < 28; ++mq) {
        f4 a0 = h0[mq], a1 = h1[mq];
#pragma unroll
        for (int e = 0; e < 4; ++e) {
            int m = mq * 4 + e;
#pragma unroll
            for (int o = 0; o < 12; ++o)
                x[o] += a0[e] * Wdec[(o * 3 + 0) * MDIM + m]
                      + a1[e] * (Wdec[(o * 3 + 1) * MDIM + m] + Wdec[(o * 3 + 2) * MDIM + m]);
        }
    }
#pragma unroll
    for (int p = 0; p < 12; ++p) {
        float s = bout[p];
#pragma unroll
        for (int o = 0; o < 12; ++o) s += Wout[p * 12 + o] * x[o];
        out[((size_t)b * 12 + p) * N_NODES + n] = s;
    }
}

// ---------------------------------------------------------------------------
extern "C" void kernel_launch(void* const* d_in, const int* in_sizes, int n_in,
                              void* d_out, int out_size, void* d_ws, size_t ws_size,
                              hipStream_t stream)
{
    const float* hist   = (const float*)d_in[0];
    const float* adj    = (const float*)d_in[1];
    const float* node_e = (const float*)d_in[2];
    const float* tid_e  = (const float*)d_in[3];
    const float* diw_e  = (const float*)d_in[4];
    const float* W_in   = (const float*)d_in[5];
    const float* b_in   = (const float*)d_in[6];
    const float* W_pre  = (const float*)d_in[7];
    const float* b_pre  = (const float*)d_in[8];
    const float* E_dy   = (const float*)d_in[9];
    const float* W_dy   = (const float*)d_in[10];
    const float* b_dy   = (const float*)d_in[11];
    const float* W_dec  = (const float*)d_in[12];
    const float* b_dec  = (const float*)d_in[13];
    const float* W_out  = (const float*)d_in[14];
    const float* b_out  = (const float*)d_in[15];
    float* out = (float*)d_out;

    float* ws = (float*)d_ws;
    const size_t XA_F   = (size_t)4096 * NCOLS_X;            // 27,787,264 floats
    const size_t ABIG_F = (size_t)4096 * KBIG / 2;           //  4,194,304 float-equiv
    const size_t XT_F   = (size_t)NCOLS_X * KBIG / 2;        //  6,946,816 float-equiv

    float* XA    = ws;                        // [4096][NCOLS_X]
    float* Ady   = ws;                        // aliases XA head; dead before gemm
    float* AbigF = ws + XA_F;
    __hip_bfloat16* Abig = (__hip_bfloat16*)AbigF;
    float* H     = AbigF;                     // aliases Abig+XT (dead after gemm)
    __hip_bfloat16* XTc = (__hip_bfloat16*)(ws + XA_F + ABIG_F);
    float* tail = ws + XA_F + ABIG_F + XT_F;
    float* na_pre = tail;                     tail += (size_t)N_NODES * 16;
    float* na_dy  = tail;                     tail += (size_t)N_NODES * 16;
    float* rs_pre = tail;                     tail += N_NODES;
    float* rs_dy  = tail;                     tail += N_NODES;
    float* Wt_pre = tail;                     tail += (size_t)KC * GDIM;
    float* Wt_dy  = tail;                     tail += (size_t)KC * GDIM;
    float* bW_pre = tail;                     tail += GDIM;
    float* bW_dy  = tail;                     tail += GDIM;
    short* WtBg   = (short*)tail;             // 2 * WTB_SH shorts

    adaptive_adj_kernel<<<N_NODES, 256, 0, stream>>>(E_dy, node_e, Ady, na_dy, rs_dy);
    node_rs_kernel<<<N_NODES, 256, 0, stream>>>(adj, node_e, na_pre, rs_pre);
    prep_wt_kernel<<<2, 256, 0, stream>>>(W_in, b_in, W_pre, Wt_pre, bW_pre);
    prep_wt_kernel<<<2, 256, 0, stream>>>(W_in, b_in, W_dy, Wt_dy, bW_dy);
    wtb_pack_kernel<<<(GDIM * KL + 255) / 256, 256, 0, stream>>>(
        Wt_pre, bW_pre, b_pre, W_pre, WtBg);
    wtb_pack_kernel<<<(GDIM * KL + 255) / 256, 256, 0, stream>>>(
        Wt_dy, bW_dy, b_dy, W_dy, WtBg + WTB_SH);

    // hi-only pack (consumes Ady), full-N build, ONE 256x128-tiled GEMM
    pack_a_kernel<<<(4096 * 2048 / 4) / 256, 256, 0, stream>>>(adj, Ady, Abig);
    build_xt_kernel<<<(NCOLS_X * 2048 / 4) / 256, 256, 0, stream>>>(hist, tid_e, diw_e, XTc);
    gemm_bf16_kernel<<<dim3(53, 16), 512, 0, stream>>>(
        (const short*)Abig, (const short*)XTc, XA);

    // fused MFMA gates + recurrence (H overwrites dead Abig/XT region)
    lstm4_kernel<<<dim3(N_NODES / 64, BATCH, 2), 256, 0, stream>>>(
        XA, WtBg, na_pre, na_dy, rs_pre, rs_dy, H);

    decode_kernel<<<(BATCH * N_NODES + 255) / 256, 256, 0, stream>>>(
        H, W_dec, b_dec, W_out, b_out, out);
}

// Round 10
// 426.999 us; speedup vs baseline: 6.5928x; 1.0239x over previous
//
#include <hip/hip_runtime.h>
#include <hip/hip_bf16.h>
#include <cstdint>
#include <cstddef>

typedef float f4 __attribute__((ext_vector_type(4)));
typedef float f4a __attribute__((ext_vector_type(4), aligned(4)));   // unaligned-tolerant
typedef short s16x8 __attribute__((ext_vector_type(8)));   // 8 bf16 in 4 VGPRs
typedef short s16x4 __attribute__((ext_vector_type(4)));

#define N_NODES 2048
#define BATCH 16
#define LSEQ 12
#define MDIM 112
#define GDIM 448                   // 4*M
#define KC 35                      // reduced contraction: 3 hist + 16 tid + 16 diw
#define NCOLS_X 6784               // KC*BATCH*LSEQ = 6720 padded to 53*128
#define KBIG 2048                  // hi-only bf16
#define KL 64                      // lstm gates contraction (35 + 3 lo + 3 lo + 18 Gc + pad)
#define WTB_SH (GDIM * KL)         // 28672 shorts = 57344 B

#define GLDS16(SRC, DST)                                                        \
    __builtin_amdgcn_global_load_lds(                                           \
        (const __attribute__((address_space(1))) void*)(SRC),                   \
        (__attribute__((address_space(3))) void*)(DST), 16, 0, 0)

#define MFMA16(ACC, AV, BV) \
    ACC = __builtin_amdgcn_mfma_f32_16x16x32_bf16(AV, BV, ACC, 0, 0, 0)

__device__ __forceinline__ short bf16hi(float v) {
    union { __hip_bfloat16 h; short s; } u;
    u.h = __float2bfloat16(v);
    return u.s;
}
__device__ __forceinline__ short bf16lo(float v) {
    union { __hip_bfloat16 h; short s; } u;
    u.h = __float2bfloat16(v);
    float r = v - __bfloat162float(u.h);
    u.h = __float2bfloat16(r);
    return u.s;
}
// fast activations: ~2ulp __expf; gate error budget dominated by bf16 (4.5e-6)
__device__ __forceinline__ float sigf_(float x)  { return 1.0f / (1.0f + __expf(-x)); }
__device__ __forceinline__ float tanhf_(float x) { return 1.0f - 2.0f / (1.0f + __expf(2.0f * x)); }

__device__ __forceinline__ float wave_sum(float v) {
#pragma unroll
    for (int off = 32; off > 0; off >>= 1) v += __shfl_down(v, off);
    return v;
}

// ---------------------------------------------------------------------------
// K1: A_dy = softmax(relu(E @ E^T), axis=1) with fused node_a/rs epilogue.
// ---------------------------------------------------------------------------
__global__ void adaptive_adj_kernel(const float* __restrict__ E,
                                    const float* __restrict__ node_emb,
                                    float* __restrict__ Ady,
                                    float* __restrict__ node_a,
                                    float* __restrict__ rs)
{
    __shared__ float sbuf[N_NODES];
    __shared__ float red[256];
    __shared__ float part[17][4];
    const int n = blockIdx.x;
    const int tid = threadIdx.x;
    float en[16];
#pragma unroll
    for (int i = 0; i < 16; ++i) en[i] = E[n * 16 + i];
    float lmax = -3.4e38f;
    for (int k = tid; k < N_NODES; k += 256) {
        const float* ek = E + k * 16;
        float d = 0.f;
#pragma unroll
        for (int i = 0; i < 16; ++i) d += en[i] * ek[i];
        d = fmaxf(d, 0.0f);
        sbuf[k] = d;
        lmax = fmaxf(lmax, d);
    }
    red[tid] = lmax; __syncthreads();
    for (int s = 128; s > 0; s >>= 1) {
        if (tid < s) red[tid] = fmaxf(red[tid], red[tid + s]);
        __syncthreads();
    }
    float mx = red[0];
    __syncthreads();
    float lsum = 0.f;
    for (int k = tid; k < N_NODES; k += 256) {
        float e = expf(sbuf[k] - mx);
        sbuf[k] = e;
        lsum += e;
    }
    red[tid] = lsum; __syncthreads();
    for (int s = 128; s > 0; s >>= 1) {
        if (tid < s) red[tid] += red[tid + s];
        __syncthreads();
    }
    float tot = red[0];
    __syncthreads();

    float p[17];
#pragma unroll
    for (int i = 0; i < 17; ++i) p[i] = 0.f;
    for (int k = tid; k < N_NODES; k += 256) {
        float a = sbuf[k] / tot;
        Ady[(size_t)n * N_NODES + k] = a;
        const float* e = node_emb + k * 16;
        p[16] += a;
#pragma unroll
        for (int i = 0; i < 16; ++i) p[i] += a * e[i];
    }
#pragma unroll
    for (int e = 0; e < 17; ++e) {
        float v = wave_sum(p[e]);
        if ((tid & 63) == 0) part[e][tid >> 6] = v;
    }
    __syncthreads();
    if (tid < 17) {
        float s = part[tid][0] + part[tid][1] + part[tid][2] + part[tid][3];
        if (tid < 16) node_a[n * 16 + tid] = s;
        else rs[n] = s;
    }
}

// ---------------------------------------------------------------------------
// K2: node_a/rs for the predefined adjacency (shuffle-reduce epilogue).
// ---------------------------------------------------------------------------
__global__ void node_rs_kernel(const float* __restrict__ A,
                               const float* __restrict__ node_emb,
                               float* __restrict__ node_a, float* __restrict__ rs)
{
    __shared__ float part[17][4];
    const int n = blockIdx.x;
    const int tid = threadIdx.x;
    float p[17];
#pragma unroll
    for (int i = 0; i < 17; ++i) p[i] = 0.f;
    for (int k = tid; k < N_NODES; k += 256) {
        float a = A[(size_t)n * N_NODES + k];
        const float* e = node_emb + k * 16;
        p[16] += a;
#pragma unroll
        for (int i = 0; i < 16; ++i) p[i] += a * e[i];
    }
#pragma unroll
    for (int e = 0; e < 17; ++e) {
        float v = wave_sum(p[e]);
        if ((tid & 63) == 0) part[e][tid >> 6] = v;
    }
    __syncthreads();
    if (tid < 17) {
        float s = part[tid][0] + part[tid][1] + part[tid][2] + part[tid][3];
        if (tid < 16) node_a[n * 16 + tid] = s;
        else rs[n] = s;
    }
}

// ---------------------------------------------------------------------------
// K3: effective weights  Wt[c][g], bW1[g]  (c = 0..2 hist, 3..34 tid/diw rows)
// ---------------------------------------------------------------------------
__global__ void prep_wt_kernel(const float* __restrict__ W_in,
                               const float* __restrict__ b_in,
                               const float* __restrict__ W,
                               float* __restrict__ Wt, float* __restrict__ bW1)
{
    int g = blockIdx.x * 256 + threadIdx.x;
    if (g >= GDIM) return;
#pragma unroll
    for (int c = 0; c < 3; ++c) {
        float s = 0.f;
        for (int m = 0; m < 64; ++m) s += W_in[c * 64 + m] * W[(size_t)m * GDIM + g];
        Wt[c * GDIM + g] = s;
    }
    float sb = 0.f;
    for (int m = 0; m < 64; ++m) sb += b_in[m] * W[(size_t)m * GDIM + g];
    bW1[g] = sb;
    for (int e = 0; e < 32; ++e)
        Wt[(3 + e) * GDIM + g] = W[(size_t)(80 + e) * GDIM + g];
}

// ---------------------------------------------------------------------------
// K4: pack gate-weight B operand for the MFMA lstm, PRE-SWIZZLED bf16.
// ---------------------------------------------------------------------------
__global__ void wtb_pack_kernel(const float* __restrict__ Wt,
                                const float* __restrict__ bW1,
                                const float* __restrict__ bg,
                                const float* __restrict__ Worig,
                                short* __restrict__ outp)
{
    int idx = blockIdx.x * 256 + threadIdx.x;      // r*64 + p
    if (idx >= GDIM * KL) return;
    int p = idx & 63;
    int r = idx >> 6;
    int tile = r >> 4, gc = r & 15;
    int mi = tile >> 2, co = tile & 3;
    int g = co * 112 + mi * 16 + gc;
    float v = 0.f; bool lo = false; bool zero = false;
    if (p < 35)        v = Wt[p * GDIM + g];
    else if (p < 38)   v = Wt[(p - 35) * GDIM + g];
    else if (p < 41) { v = Wt[(p - 38) * GDIM + g]; lo = true; }
    else if (p == 41)  v = bg[g];
    else if (p == 42)  v = bW1[g];
    else if (p < 59)   v = Worig[(size_t)(64 + p - 43) * GDIM + g];
    else if (p == 59) { v = bg[g]; lo = true; }
    else if (p == 60) { v = bW1[g]; lo = true; }
    else zero = true;
    short s = zero ? (short)0 : (lo ? bf16lo(v) : bf16hi(v));
    int a = r * 128 + p * 2;
    int asw = a ^ (((a >> 7) & 7) << 4);
    outp[asw >> 1] = s;
}

// ---------------------------------------------------------------------------
// K5: hi-only bf16 pack of stacked adjacency, 4-wide vectorized.
// ---------------------------------------------------------------------------
__global__ void pack_a_kernel(const float* __restrict__ adj,
                              const float* __restrict__ Ady,
                              __hip_bfloat16* __restrict__ Abig)
{
    int idx = blockIdx.x * 256 + threadIdx.x;    // each handles 4 consecutive k
    int e0 = idx << 2;
    int k = e0 & 2047;
    int m = e0 >> 11;
    const float* src = (m < 2048) ? adj + ((size_t)m * 2048 + k)
                                  : Ady + ((size_t)(m - 2048) * 2048 + k);
    f4 v = *(const f4*)src;
    s16x4 o = { bf16hi(v[0]), bf16hi(v[1]), bf16hi(v[2]), bf16hi(v[3]) };
    *(s16x4*)((short*)Abig + (size_t)m * KBIG + k) = o;
}

// ---------------------------------------------------------------------------
// K6: build transposed hi-only B: XT[jl][k] (bf16), 4-wide per thread.
// ---------------------------------------------------------------------------
__global__ void build_xt_kernel(const float* __restrict__ hist,
                                const float* __restrict__ tid_emb,
                                const float* __restrict__ diw_emb,
                                __hip_bfloat16* __restrict__ XT)
{
    int idx = blockIdx.x * 256 + threadIdx.x;    // < NCOLS_X*2048/4
    int e0 = idx << 2;
    int k0 = e0 & 2047;
    int jl = e0 >> 11;
    s16x4 o = {0, 0, 0, 0};
    if (jl < KC * BATCH * LSEQ) {
        int c = jl % KC;
        int bl = jl / KC;
#pragma unroll
        for (int i = 0; i < 4; ++i) {
            const float* h = hist + ((size_t)(bl * N_NODES + k0 + i)) * 3;
            float v;
            if (c < 3) v = h[c];
            else if (c < 19) { int ti = (int)(h[1] * 288.0f); v = tid_emb[ti * 16 + (c - 3)]; }
            else             { int di = (int)(h[2] * 7.0f);   v = diw_emb[di * 16 + (c - 19)]; }
            o[i] = bf16hi(v);
        }
    }
    *(s16x4*)((short*)XT + (size_t)jl * KBIG + k0) = o;
}

// ---------------------------------------------------------------------------
// K7: bf16 MFMA GEMM: C[4096][6784] = Abig[4096][2048] @ XT^T.
// 256x128 tile, BK=32, 512 threads (8 waves, 4x2), column-major XCD swizzle.
// ---------------------------------------------------------------------------
__global__ __launch_bounds__(512, 4) void gemm_bf16_kernel(const short* __restrict__ A,
                                                           const short* __restrict__ BT,
                                                           float* __restrict__ C)
{
    __shared__ short As[256 * 32];     // 16 KB
    __shared__ short Bs[128 * 32];     //  8 KB
    const int tid = threadIdx.x;
    const int w = tid >> 6;            // wave 0..7
    const int l = tid & 63;
    const int wr = w >> 1;             // 0..3 -> 64-row band
    const int wc = w & 1;              // 0..1 -> 64-col band

    const int bid = blockIdx.y * 53 + blockIdx.x;        // 0..847
    const int sid = (bid & 7) * 106 + (bid >> 3);        // XCD-contiguous
    const int col = sid >> 4;                            // 0..52 (column-major)
    const int row = sid & 15;                            // 0..15
    const int m0 = row * 256;
    const int jt = col * 128;

    const int arow0 = tid >> 2;                 // A chunk 0: rows 0..127
    const int akc   = (tid & 3) * 8;            // k-octet (shorts)
    const size_t gA0 = (size_t)(m0 + arow0) * KBIG + akc;
    const size_t gA1 = (size_t)(m0 + 128 + arow0) * KBIG + akc;
    const size_t gB0 = (size_t)(jt + arow0) * KBIG + akc;
    char* lA0 = (char*)As + tid * 16;
    char* lA1 = (char*)As + 8192 + tid * 16;
    char* lB0 = (char*)Bs + tid * 16;

    f4 acc[4][4];
#pragma unroll
    for (int i = 0; i < 4; ++i)
#pragma unroll
        for (int j = 0; j < 4; ++j)
#pragma unroll
            for (int e = 0; e < 4; ++e) acc[i][j][e] = 0.f;

    const int fkof = (l >> 4) * 8;              // k-offset within frag (shorts)

    for (int kt = 0; kt < KBIG; kt += 32) {
        __syncthreads();
        GLDS16(A  + gA0 + kt, lA0);
        GLDS16(A  + gA1 + kt, lA1);
        GLDS16(BT + gB0 + kt, lB0);
        __syncthreads();
        s16x8 a[4], b[4];
#pragma unroll
        for (int mi = 0; mi < 4; ++mi)
            a[mi] = *(const s16x8*)&As[(wr * 64 + mi * 16 + (l & 15)) * 32 + fkof];
#pragma unroll
        for (int ni = 0; ni < 4; ++ni)
            b[ni] = *(const s16x8*)&Bs[(wc * 64 + ni * 16 + (l & 15)) * 32 + fkof];
#pragma unroll
        for (int mi = 0; mi < 4; ++mi)
#pragma unroll
            for (int ni = 0; ni < 4; ++ni)
                MFMA16(acc[mi][ni], a[mi], b[ni]);
    }

    const int rbase = m0 + wr * 64 + (l >> 4) * 4;
    const int cbase = jt + wc * 64 + (l & 15);
#pragma unroll
    for (int mi = 0; mi < 4; ++mi)
#pragma unroll
        for (int ni = 0; ni < 4; ++ni)
#pragma unroll
            for (int reg = 0; reg < 4; ++reg)
                C[(size_t)(rbase + mi * 16 + reg) * NCOLS_X + cbase + ni * 16] =
                    acc[mi][ni][reg];
}

// ---------------------------------------------------------------------------
// K8: fused MFMA gates + LSTM c-recurrence, v5.
// 512 threads / 128 nodes per block -> LDS 72 KB, 2 blocks/CU = 4 waves/SIMD
// (was 2).  f4-vectorized XA reads (16 scalar loads -> 4 vec loads) with
// T14 async prefetch: t+1's loads issue right after the post-write barrier,
// hiding under compute(t) (previous layout drained them at the barrier).
// Math identical to lstm4 (bit-exact).
// ---------------------------------------------------------------------------
__global__ __launch_bounds__(512, 4) void lstm5_kernel(
    const float* __restrict__ XA,
    const short* __restrict__ WtBg,            // [2][WTB_SH] pre-swizzled
    const float* __restrict__ na_pre, const float* __restrict__ na_dy,
    const float* __restrict__ rs_pre, const float* __restrict__ rs_dy,
    float* __restrict__ H)
{
    __shared__ short sWtb[WTB_SH];             // 57344 B
    __shared__ short sXa[128 * KL];            // 16384 B
    const int tid = threadIdx.x;
    const int w = tid >> 6, l = tid & 63;      // 8 waves
    const int n0 = blockIdx.x * 128;
    const int b  = blockIdx.y;
    const int z  = blockIdx.z;
    const float* na = z ? na_dy : na_pre;
    const float* rs = z ? rs_dy : rs_pre;

    // stage WtB via global_load_lds: 3584 16B-chunks = 8 waves x 7 iters
    {
        const char* gW = (const char*)(WtBg + (size_t)z * WTB_SH);
        char* lW = (char*)sWtb;
        for (int it = 0; it < 7; ++it) {
            int base = (it * 8 + w) * 64;
            GLDS16(gW + (size_t)(base + l) * 16, lW + base * 16);
        }
    }

    // staging identities: thread -> (row sr, k-quarter pp)
    const int sr = tid & 127;
    const int pp = tid >> 7;
    const float* xarow = XA + (size_t)(z * 2048 + n0 + sr) * NCOLS_X;
    const float* narow = na + (size_t)(n0 + sr) * 16;
    const float rsv = rs[n0 + sr];
    char* wrow = (char*)sXa + sr * 128;
    const int wswz = (sr & 7) << 4;

    // compute identities
    const int lm = l & 15;
    const int sm = (l & 7) << 4;
    const int kof0 = ((l >> 4) * 16) ^ sm;
    const int kof1 = (64 + (l >> 4) * 16) ^ sm;
    const int an = w * 16 + lm;                // 0..127
    const char* xab = (const char*)sXa;
    const char* wtbb = (const char*)sWtb;
    float* Hout = H + (size_t)z * BATCH * N_NODES * MDIM;

    float cc[7][4];
#pragma unroll
    for (int mi = 0; mi < 7; ++mi)
#pragma unroll
        for (int q = 0; q < 4; ++q) cc[mi][q] = 0.f;

    // prefetch t = 0
    f4 pf0 = {0,0,0,0}, pf1 = pf0, pf2 = pf0, pf3 = pf0;
    {
        const int col0 = (b * LSEQ + 0) * KC;
        if (pp < 2) {
            const float* s = xarow + col0 + pp * 16;
            pf0 = *(const f4a*)(s);
            pf1 = *(const f4a*)(s + 4);
            pf2 = *(const f4a*)(s + 8);
            pf3 = *(const f4a*)(s + 12);
        } else if (pp == 2) {
            pf0 = *(const f4a*)(xarow + col0);        // cols 0..3
            pf1 = *(const f4a*)(xarow + col0 + 32);   // cols 32..35
        }
    }

    for (int t = 0; t < LSEQ; ++t) {
        __syncthreads();     // prior compute's sXa reads done; drains pf (and WtB DMA at t=0)
        {
            short v[16];
            if (pp < 2) {
#pragma unroll
                for (int e = 0; e < 4; ++e) {
                    v[e]      = bf16hi(pf0[e]);
                    v[4 + e]  = bf16hi(pf1[e]);
                    v[8 + e]  = bf16hi(pf2[e]);
                    v[12 + e] = bf16hi(pf3[e]);
                }
            } else if (pp == 2) {
                v[0] = bf16hi(pf1[0]);
                v[1] = bf16hi(pf1[1]);
                v[2] = bf16hi(pf1[2]);
                v[3] = bf16lo(pf0[0]);
                v[4] = bf16lo(pf0[1]);
                v[5] = bf16lo(pf0[2]);
                v[6] = bf16hi(pf0[0]);
                v[7] = bf16hi(pf0[1]);
                v[8] = bf16hi(pf0[2]);
                v[9]  = bf16hi(1.0f);
                v[10] = bf16hi(rsv);
#pragma unroll
                for (int j = 11; j < 16; ++j) v[j] = bf16hi(narow[j - 11]);
            } else {
#pragma unroll
                for (int j = 0; j < 11; ++j) v[j] = bf16hi(narow[5 + j]);
                v[11] = bf16hi(1.0f);
                v[12] = bf16hi(rsv);
                v[13] = 0; v[14] = 0; v[15] = 0;
            }
#pragma unroll
            for (int q = 0; q < 4; ++q) {
                s16x4 sv = { v[q * 4], v[q * 4 + 1], v[q * 4 + 2], v[q * 4 + 3] };
                *(s16x4*)(wrow + ((pp * 32 + q * 8) ^ wswz)) = sv;
            }
        }
        __syncthreads();     // sXa(t) visible; no outstanding vmem here

        // T14: issue t+1 loads now — latency hides under compute(t)
        if (t + 1 < LSEQ) {
            const int col0 = (b * LSEQ + t + 1) * KC;
            if (pp < 2) {
                const float* s = xarow + col0 + pp * 16;
                pf0 = *(const f4a*)(s);
                pf1 = *(const f4a*)(s + 4);
                pf2 = *(const f4a*)(s + 8);
                pf3 = *(const f4a*)(s + 12);
            } else if (pp == 2) {
                pf0 = *(const f4a*)(xarow + col0);
                pf1 = *(const f4a*)(xarow + col0 + 32);
            }
        }

        s16x8 a0 = *(const s16x8*)(xab + an * 128 + kof0);
        s16x8 a1 = *(const s16x8*)(xab + an * 128 + kof1);
#pragma unroll
        for (int mi = 0; mi < 7; ++mi) {
            const char* bb = wtbb + (mi * 64 + lm) * 128;   // co=0 row; co step = +2048B
            f4 gi = {0.f, 0.f, 0.f, 0.f};
            f4 gf = gi, gg = gi;
            MFMA16(gi, a0, *(const s16x8*)(bb + kof0));
            MFMA16(gi, a1, *(const s16x8*)(bb + kof1));
            MFMA16(gf, a0, *(const s16x8*)(bb + 2048 + kof0));
            MFMA16(gf, a1, *(const s16x8*)(bb + 2048 + kof1));
            MFMA16(gg, a0, *(const s16x8*)(bb + 4096 + kof0));
            MFMA16(gg, a1, *(const s16x8*)(bb + 4096 + kof1));
#pragma unroll
            for (int q = 0; q < 4; ++q) {
                float si = sigf_(gi[q]);
                float sf = sigf_(gf[q]);
                float tg = tanhf_(gg[q]);
                cc[mi][q] = sf * cc[mi][q] + si * tg;
            }
            if (t == LSEQ - 1) {
                f4 go = {0.f, 0.f, 0.f, 0.f};
                MFMA16(go, a0, *(const s16x8*)(bb + 6144 + kof0));
                MFMA16(go, a1, *(const s16x8*)(bb + 6144 + kof1));
#pragma unroll
                for (int q = 0; q < 4; ++q) {
                    float h = sigf_(go[q]) * tanhf_(cc[mi][q]);
                    Hout[((size_t)b * N_NODES + n0 + w * 16 + (l >> 4) * 4 + q) * MDIM
                         + mi * 16 + lm] = h;
                }
            }
        }
    }
}

// ---------------------------------------------------------------------------
// K9: fused decoder, f4-vectorized H loads.
// ---------------------------------------------------------------------------
__global__ void decode_kernel(const float* __restrict__ H,
                              const float* __restrict__ Wdec,
                              const float* __restrict__ bdec,
                              const float* __restrict__ Wout,
                              const float* __restrict__ bout,
                              float* __restrict__ out)
{
    int g = blockIdx.x * 256 + threadIdx.x;   // g = b*2048 + n
    if (g >= BATCH * N_NODES) return;
    int b = g >> 11;
    int n = g & 2047;
    const f4* h0 = (const f4*)(H + (size_t)g * MDIM);
    const f4* h1 = (const f4*)(H + (size_t)BATCH * N_NODES * MDIM + (size_t)g * MDIM);
    float x[12];
#pragma unroll
    for (int o = 0; o < 12; ++o) x[o] = bdec[o];
    for (int mq = 0; mq < 28; ++mq) {
        f4 a0 = h0[mq], a1 = h1[mq];
#pragma unroll
        for (int e = 0; e < 4; ++e) {
            int m = mq * 4 + e;
#pragma unroll
            for (int o = 0; o < 12; ++o)
                x[o] += a0[e] * Wdec[(o * 3 + 0) * MDIM + m]
                      + a1[e] * (Wdec[(o * 3 + 1) * MDIM + m] + Wdec[(o * 3 + 2) * MDIM + m]);
        }
    }
#pragma unroll
    for (int p = 0; p < 12; ++p) {
        float s = bout[p];
#pragma unroll
        for (int o = 0; o < 12; ++o) s += Wout[p * 12 + o] * x[o];
        out[((size_t)b * 12 + p) * N_NODES + n] = s;
    }
}

// ---------------------------------------------------------------------------
extern "C" void kernel_launch(void* const* d_in, const int* in_sizes, int n_in,
                              void* d_out, int out_size, void* d_ws, size_t ws_size,
                              hipStream_t stream)
{
    const float* hist   = (const float*)d_in[0];
    const float* adj    = (const float*)d_in[1];
    const float* node_e = (const float*)d_in[2];
    const float* tid_e  = (const float*)d_in[3];
    const float* diw_e  = (const float*)d_in[4];
    const float* W_in   = (const float*)d_in[5];
    const float* b_in   = (const float*)d_in[6];
    const float* W_pre  = (const float*)d_in[7];
    const float* b_pre  = (const float*)d_in[8];
    const float* E_dy   = (const float*)d_in[9];
    const float* W_dy   = (const float*)d_in[10];
    const float* b_dy   = (const float*)d_in[11];
    const float* W_dec  = (const float*)d_in[12];
    const float* b_dec  = (const float*)d_in[13];
    const float* W_out  = (const float*)d_in[14];
    const float* b_out  = (const float*)d_in[15];
    float* out = (float*)d_out;

    float* ws = (float*)d_ws;
    const size_t XA_F   = (size_t)4096 * NCOLS_X;            // 27,787,264 floats
    const size_t ABIG_F = (size_t)4096 * KBIG / 2;           //  4,194,304 float-equiv
    const size_t XT_F   = (size_t)NCOLS_X * KBIG / 2;        //  6,946,816 float-equiv

    float* XA    = ws;                        // [4096][NCOLS_X]
    float* Ady   = ws;                        // aliases XA head; dead before gemm
    float* AbigF = ws + XA_F;
    __hip_bfloat16* Abig = (__hip_bfloat16*)AbigF;
    float* H     = AbigF;                     // aliases Abig+XT (dead after gemm)
    __hip_bfloat16* XTc = (__hip_bfloat16*)(ws + XA_F + ABIG_F);
    float* tail = ws + XA_F + ABIG_F + XT_F;
    float* na_pre = tail;                     tail += (size_t)N_NODES * 16;
    float* na_dy  = tail;                     tail += (size_t)N_NODES * 16;
    float* rs_pre = tail;                     tail += N_NODES;
    float* rs_dy  = tail;                     tail += N_NODES;
    float* Wt_pre = tail;                     tail += (size_t)KC * GDIM;
    float* Wt_dy  = tail;                     tail += (size_t)KC * GDIM;
    float* bW_pre = tail;                     tail += GDIM;
    float* bW_dy  = tail;                     tail += GDIM;
    short* WtBg   = (short*)tail;             // 2 * WTB_SH shorts

    adaptive_adj_kernel<<<N_NODES, 256, 0, stream>>>(E_dy, node_e, Ady, na_dy, rs_dy);
    node_rs_kernel<<<N_NODES, 256, 0, stream>>>(adj, node_e, na_pre, rs_pre);
    prep_wt_kernel<<<2, 256, 0, stream>>>(W_in, b_in, W_pre, Wt_pre, bW_pre);
    prep_wt_kernel<<<2, 256, 0, stream>>>(W_in, b_in, W_dy, Wt_dy, bW_dy);
    wtb_pack_kernel<<<(GDIM * KL + 255) / 256, 256, 0, stream>>>(
        Wt_pre, bW_pre, b_pre, W_pre, WtBg);
    wtb_pack_kernel<<<(GDIM * KL + 255) / 256, 256, 0, stream>>>(
        Wt_dy, bW_dy, b_dy, W_dy, WtBg + WTB_SH);

    // hi-only pack (consumes Ady), full-N build, ONE 256x128-tiled GEMM
    pack_a_kernel<<<(4096 * 2048 / 4) / 256, 256, 0, stream>>>(adj, Ady, Abig);
    build_xt_kernel<<<(NCOLS_X * 2048 / 4) / 256, 256, 0, stream>>>(hist, tid_e, diw_e, XTc);
    gemm_bf16_kernel<<<dim3(53, 16), 512, 0, stream>>>(
        (const short*)Abig, (const short*)XTc, XA);

    // fused MFMA gates + recurrence (H overwrites dead Abig/XT region)
    lstm5_kernel<<<dim3(N_NODES / 128, BATCH, 2), 512, 0, stream>>>(
        XA, WtBg, na_pre, na_dy, rs_pre, rs_dy, H);

    decode_kernel<<<(BATCH * N_NODES + 255) / 256, 256, 0, stream>>>(
        H, W_dec, b_dec, W_out, b_out, out);
}

// Round 11
// 354.526 us; speedup vs baseline: 7.9405x; 1.2044x over previous
//
#include <hip/hip_runtime.h>
#include <hip/hip_bf16.h>
#include <cstdint>
#include <cstddef>

typedef float f4 __attribute__((ext_vector_type(4)));
typedef float f4a __attribute__((ext_vector_type(4), aligned(4)));   // unaligned-tolerant
typedef short s16x8 __attribute__((ext_vector_type(8)));   // 8 bf16 in 4 VGPRs
typedef short s16x4 __attribute__((ext_vector_type(4)));

#define N_NODES 2048
#define BATCH 16
#define LSEQ 12
#define MDIM 112
#define GDIM 448                   // 4*M
#define KC 35                      // reduced contraction: 3 hist + 16 tid + 16 diw
#define NCOLS_X 6784               // KC*BATCH*LSEQ = 6720 padded to 53*128
#define KBIG 2048                  // hi-only bf16
#define KL 64                      // lstm gates contraction (35 + 3 lo + 3 lo + 18 Gc + pad)
#define WTB_SH (GDIM * KL)         // 28672 shorts = 57344 B

#define GLDS16(SRC, DST)                                                        \
    __builtin_amdgcn_global_load_lds(                                           \
        (const __attribute__((address_space(1))) void*)(SRC),                   \
        (__attribute__((address_space(3))) void*)(DST), 16, 0, 0)

#define MFMA16(ACC, AV, BV) \
    ACC = __builtin_amdgcn_mfma_f32_16x16x32_bf16(AV, BV, ACC, 0, 0, 0)

__device__ __forceinline__ short bf16hi(float v) {
    union { __hip_bfloat16 h; short s; } u;
    u.h = __float2bfloat16(v);
    return u.s;
}
__device__ __forceinline__ short bf16lo(float v) {
    union { __hip_bfloat16 h; short s; } u;
    u.h = __float2bfloat16(v);
    float r = v - __bfloat162float(u.h);
    u.h = __float2bfloat16(r);
    return u.s;
}
// native-rate activations: v_exp + v_rcp (~1-2 ulp each). Without these the
// compiler expands each fp32 divide to the ~10-inst IEEE div sequence, which
// made lstm VALU-bound (R10: VALUBusy 79%, MfmaUtil 9).
__device__ __forceinline__ float rcpf_(float x)  { return __builtin_amdgcn_rcpf(x); }
__device__ __forceinline__ float sigf_(float x)  { return rcpf_(1.0f + __expf(-x)); }
__device__ __forceinline__ float tanhf_(float x) { return 1.0f - 2.0f * rcpf_(1.0f + __expf(2.0f * x)); }

__device__ __forceinline__ float wave_sum(float v) {
#pragma unroll
    for (int off = 32; off > 0; off >>= 1) v += __shfl_down(v, off);
    return v;
}

// ---------------------------------------------------------------------------
// K1: A_dy = softmax(relu(E @ E^T), axis=1).  Writes bf16 rows DIRECTLY into
// Abig[2048+n] (fp32 Ady round-trip removed) + fused node_a/rs epilogue.
// ---------------------------------------------------------------------------
__global__ void adaptive_adj_kernel(const float* __restrict__ E,
                                    const float* __restrict__ node_emb,
                                    __hip_bfloat16* __restrict__ Abig,
                                    float* __restrict__ node_a,
                                    float* __restrict__ rs)
{
    __shared__ float sbuf[N_NODES];
    __shared__ float red[256];
    __shared__ float part[17][4];
    const int n = blockIdx.x;
    const int tid = threadIdx.x;
    float en[16];
#pragma unroll
    for (int i = 0; i < 16; ++i) en[i] = E[n * 16 + i];
    float lmax = -3.4e38f;
    for (int k = tid; k < N_NODES; k += 256) {
        const float* ek = E + k * 16;
        float d = 0.f;
#pragma unroll
        for (int i = 0; i < 16; ++i) d += en[i] * ek[i];
        d = fmaxf(d, 0.0f);
        sbuf[k] = d;
        lmax = fmaxf(lmax, d);
    }
    red[tid] = lmax; __syncthreads();
    for (int s = 128; s > 0; s >>= 1) {
        if (tid < s) red[tid] = fmaxf(red[tid], red[tid + s]);
        __syncthreads();
    }
    float mx = red[0];
    __syncthreads();
    float lsum = 0.f;
    for (int k = tid; k < N_NODES; k += 256) {
        float e = __expf(sbuf[k] - mx);
        sbuf[k] = e;
        lsum += e;
    }
    red[tid] = lsum; __syncthreads();
    for (int s = 128; s > 0; s >>= 1) {
        if (tid < s) red[tid] += red[tid + s];
        __syncthreads();
    }
    float rinv = rcpf_(red[0]);
    __syncthreads();

    __hip_bfloat16* arow = Abig + (size_t)(2048 + n) * KBIG;
    float p[17];
#pragma unroll
    for (int i = 0; i < 17; ++i) p[i] = 0.f;
    for (int k = tid; k < N_NODES; k += 256) {
        float a = sbuf[k] * rinv;
        arow[k] = __float2bfloat16(a);
        const float* e = node_emb + k * 16;
        p[16] += a;
#pragma unroll
        for (int i = 0; i < 16; ++i) p[i] += a * e[i];
    }
#pragma unroll
    for (int e = 0; e < 17; ++e) {
        float v = wave_sum(p[e]);
        if ((tid & 63) == 0) part[e][tid >> 6] = v;
    }
    __syncthreads();
    if (tid < 17) {
        float s = part[tid][0] + part[tid][1] + part[tid][2] + part[tid][3];
        if (tid < 16) node_a[n * 16 + tid] = s;
        else rs[n] = s;
    }
}

// ---------------------------------------------------------------------------
// K2: node_a/rs for the predefined adjacency (shuffle-reduce epilogue).
// ---------------------------------------------------------------------------
__global__ void node_rs_kernel(const float* __restrict__ A,
                               const float* __restrict__ node_emb,
                               float* __restrict__ node_a, float* __restrict__ rs)
{
    __shared__ float part[17][4];
    const int n = blockIdx.x;
    const int tid = threadIdx.x;
    float p[17];
#pragma unroll
    for (int i = 0; i < 17; ++i) p[i] = 0.f;
    for (int k = tid; k < N_NODES; k += 256) {
        float a = A[(size_t)n * N_NODES + k];
        const float* e = node_emb + k * 16;
        p[16] += a;
#pragma unroll
        for (int i = 0; i < 16; ++i) p[i] += a * e[i];
    }
#pragma unroll
    for (int e = 0; e < 17; ++e) {
        float v = wave_sum(p[e]);
        if ((tid & 63) == 0) part[e][tid >> 6] = v;
    }
    __syncthreads();
    if (tid < 17) {
        float s = part[tid][0] + part[tid][1] + part[tid][2] + part[tid][3];
        if (tid < 16) node_a[n * 16 + tid] = s;
        else rs[n] = s;
    }
}

// ---------------------------------------------------------------------------
// K3: effective weights  Wt[c][g], bW1[g]  (c = 0..2 hist, 3..34 tid/diw rows)
// ---------------------------------------------------------------------------
__global__ void prep_wt_kernel(const float* __restrict__ W_in,
                               const float* __restrict__ b_in,
                               const float* __restrict__ W,
                               float* __restrict__ Wt, float* __restrict__ bW1)
{
    int g = blockIdx.x * 256 + threadIdx.x;
    if (g >= GDIM) return;
#pragma unroll
    for (int c = 0; c < 3; ++c) {
        float s = 0.f;
        for (int m = 0; m < 64; ++m) s += W_in[c * 64 + m] * W[(size_t)m * GDIM + g];
        Wt[c * GDIM + g] = s;
    }
    float sb = 0.f;
    for (int m = 0; m < 64; ++m) sb += b_in[m] * W[(size_t)m * GDIM + g];
    bW1[g] = sb;
    for (int e = 0; e < 32; ++e)
        Wt[(3 + e) * GDIM + g] = W[(size_t)(80 + e) * GDIM + g];
}

// ---------------------------------------------------------------------------
// K4: pack gate-weight B operand for the MFMA lstm, PRE-SWIZZLED bf16.
// ---------------------------------------------------------------------------
__global__ void wtb_pack_kernel(const float* __restrict__ Wt,
                                const float* __restrict__ bW1,
                                const float* __restrict__ bg,
                                const float* __restrict__ Worig,
                                short* __restrict__ outp)
{
    int idx = blockIdx.x * 256 + threadIdx.x;      // r*64 + p
    if (idx >= GDIM * KL) return;
    int p = idx & 63;
    int r = idx >> 6;
    int tile = r >> 4, gc = r & 15;
    int mi = tile >> 2, co = tile & 3;
    int g = co * 112 + mi * 16 + gc;
    float v = 0.f; bool lo = false; bool zero = false;
    if (p < 35)        v = Wt[p * GDIM + g];
    else if (p < 38)   v = Wt[(p - 35) * GDIM + g];
    else if (p < 41) { v = Wt[(p - 38) * GDIM + g]; lo = true; }
    else if (p == 41)  v = bg[g];
    else if (p == 42)  v = bW1[g];
    else if (p < 59)   v = Worig[(size_t)(64 + p - 43) * GDIM + g];
    else if (p == 59) { v = bg[g]; lo = true; }
    else if (p == 60) { v = bW1[g]; lo = true; }
    else zero = true;
    short s = zero ? (short)0 : (lo ? bf16lo(v) : bf16hi(v));
    int a = r * 128 + p * 2;
    int asw = a ^ (((a >> 7) & 7) << 4);
    outp[asw >> 1] = s;
}

// ---------------------------------------------------------------------------
// K5: hi-only bf16 pack of the PREDEFINED adjacency (rows 0..2047 of Abig;
// dynamic rows are written by adaptive_adj directly).
// ---------------------------------------------------------------------------
__global__ void pack_a_kernel(const float* __restrict__ adj,
                              __hip_bfloat16* __restrict__ Abig)
{
    int idx = blockIdx.x * 256 + threadIdx.x;    // each handles 4 consecutive k
    int e0 = idx << 2;
    int k = e0 & 2047;
    int m = e0 >> 11;                            // 0..2047
    f4 v = *(const f4*)(adj + (size_t)m * 2048 + k);
    s16x4 o = { bf16hi(v[0]), bf16hi(v[1]), bf16hi(v[2]), bf16hi(v[3]) };
    *(s16x4*)((short*)Abig + (size_t)m * KBIG + k) = o;
}

// ---------------------------------------------------------------------------
// K6: build transposed hi-only B: XT[jl][k] (bf16), 4-wide per thread.
// ---------------------------------------------------------------------------
__global__ void build_xt_kernel(const float* __restrict__ hist,
                                const float* __restrict__ tid_emb,
                                const float* __restrict__ diw_emb,
                                __hip_bfloat16* __restrict__ XT)
{
    int idx = blockIdx.x * 256 + threadIdx.x;    // < NCOLS_X*2048/4
    int e0 = idx << 2;
    int k0 = e0 & 2047;
    int jl = e0 >> 11;
    s16x4 o = {0, 0, 0, 0};
    if (jl < KC * BATCH * LSEQ) {
        int c = jl % KC;
        int bl = jl / KC;
#pragma unroll
        for (int i = 0; i < 4; ++i) {
            const float* h = hist + ((size_t)(bl * N_NODES + k0 + i)) * 3;
            float v;
            if (c < 3) v = h[c];
            else if (c < 19) { int ti = (int)(h[1] * 288.0f); v = tid_emb[ti * 16 + (c - 3)]; }
            else             { int di = (int)(h[2] * 7.0f);   v = diw_emb[di * 16 + (c - 19)]; }
            o[i] = bf16hi(v);
        }
    }
    *(s16x4*)((short*)XT + (size_t)jl * KBIG + k0) = o;
}

// ---------------------------------------------------------------------------
// K7: bf16 MFMA GEMM: C[4096][6784] = Abig[4096][2048] @ XT^T.
// 256x128 tile, BK=32, 512 threads (8 waves, 4x2), column-major XCD swizzle.
// ---------------------------------------------------------------------------
__global__ __launch_bounds__(512, 4) void gemm_bf16_kernel(const short* __restrict__ A,
                                                           const short* __restrict__ BT,
                                                           float* __restrict__ C)
{
    __shared__ short As[256 * 32];     // 16 KB
    __shared__ short Bs[128 * 32];     //  8 KB
    const int tid = threadIdx.x;
    const int w = tid >> 6;            // wave 0..7
    const int l = tid & 63;
    const int wr = w >> 1;             // 0..3 -> 64-row band
    const int wc = w & 1;              // 0..1 -> 64-col band

    const int bid = blockIdx.y * 53 + blockIdx.x;        // 0..847
    const int sid = (bid & 7) * 106 + (bid >> 3);        // XCD-contiguous
    const int col = sid >> 4;                            // 0..52 (column-major)
    const int row = sid & 15;                            // 0..15
    const int m0 = row * 256;
    const int jt = col * 128;

    const int arow0 = tid >> 2;                 // A chunk 0: rows 0..127
    const int akc   = (tid & 3) * 8;            // k-octet (shorts)
    const size_t gA0 = (size_t)(m0 + arow0) * KBIG + akc;
    const size_t gA1 = (size_t)(m0 + 128 + arow0) * KBIG + akc;
    const size_t gB0 = (size_t)(jt + arow0) * KBIG + akc;
    char* lA0 = (char*)As + tid * 16;
    char* lA1 = (char*)As + 8192 + tid * 16;
    char* lB0 = (char*)Bs + tid * 16;

    f4 acc[4][4];
#pragma unroll
    for (int i = 0; i < 4; ++i)
#pragma unroll
        for (int j = 0; j < 4; ++j)
#pragma unroll
            for (int e = 0; e < 4; ++e) acc[i][j][e] = 0.f;

    const int fkof = (l >> 4) * 8;              // k-offset within frag (shorts)

    for (int kt = 0; kt < KBIG; kt += 32) {
        __syncthreads();
        GLDS16(A  + gA0 + kt, lA0);
        GLDS16(A  + gA1 + kt, lA1);
        GLDS16(BT + gB0 + kt, lB0);
        __syncthreads();
        s16x8 a[4], b[4];
#pragma unroll
        for (int mi = 0; mi < 4; ++mi)
            a[mi] = *(const s16x8*)&As[(wr * 64 + mi * 16 + (l & 15)) * 32 + fkof];
#pragma unroll
        for (int ni = 0; ni < 4; ++ni)
            b[ni] = *(const s16x8*)&Bs[(wc * 64 + ni * 16 + (l & 15)) * 32 + fkof];
#pragma unroll
        for (int mi = 0; mi < 4; ++mi)
#pragma unroll
            for (int ni = 0; ni < 4; ++ni)
                MFMA16(acc[mi][ni], a[mi], b[ni]);
    }

    const int rbase = m0 + wr * 64 + (l >> 4) * 4;
    const int cbase = jt + wc * 64 + (l & 15);
#pragma unroll
    for (int mi = 0; mi < 4; ++mi)
#pragma unroll
        for (int ni = 0; ni < 4; ++ni)
#pragma unroll
            for (int reg = 0; reg < 4; ++reg)
                C[(size_t)(rbase + mi * 16 + reg) * NCOLS_X + cbase + ni * 16] =
                    acc[mi][ni][reg];
}

// ---------------------------------------------------------------------------
// K8: fused MFMA gates + LSTM c-recurrence, v5 + native-rcp activations.
// 512 threads / 128 nodes per block; T14 async XA prefetch.
// ---------------------------------------------------------------------------
__global__ __launch_bounds__(512, 4) void lstm5_kernel(
    const float* __restrict__ XA,
    const short* __restrict__ WtBg,            // [2][WTB_SH] pre-swizzled
    const float* __restrict__ na_pre, const float* __restrict__ na_dy,
    const float* __restrict__ rs_pre, const float* __restrict__ rs_dy,
    float* __restrict__ H)
{
    __shared__ short sWtb[WTB_SH];             // 57344 B
    __shared__ short sXa[128 * KL];            // 16384 B
    const int tid = threadIdx.x;
    const int w = tid >> 6, l = tid & 63;      // 8 waves
    const int n0 = blockIdx.x * 128;
    const int b  = blockIdx.y;
    const int z  = blockIdx.z;
    const float* na = z ? na_dy : na_pre;
    const float* rs = z ? rs_dy : rs_pre;

    // stage WtB via global_load_lds: 3584 16B-chunks = 8 waves x 7 iters
    {
        const char* gW = (const char*)(WtBg + (size_t)z * WTB_SH);
        char* lW = (char*)sWtb;
        for (int it = 0; it < 7; ++it) {
            int base = (it * 8 + w) * 64;
            GLDS16(gW + (size_t)(base + l) * 16, lW + base * 16);
        }
    }

    // staging identities: thread -> (row sr, k-quarter pp)
    const int sr = tid & 127;
    const int pp = tid >> 7;
    const float* xarow = XA + (size_t)(z * 2048 + n0 + sr) * NCOLS_X;
    const float* narow = na + (size_t)(n0 + sr) * 16;
    const float rsv = rs[n0 + sr];
    char* wrow = (char*)sXa + sr * 128;
    const int wswz = (sr & 7) << 4;

    // compute identities
    const int lm = l & 15;
    const int sm = (l & 7) << 4;
    const int kof0 = ((l >> 4) * 16) ^ sm;
    const int kof1 = (64 + (l >> 4) * 16) ^ sm;
    const int an = w * 16 + lm;                // 0..127
    const char* xab = (const char*)sXa;
    const char* wtbb = (const char*)sWtb;
    float* Hout = H + (size_t)z * BATCH * N_NODES * MDIM;

    float cc[7][4];
#pragma unroll
    for (int mi = 0; mi < 7; ++mi)
#pragma unroll
        for (int q = 0; q < 4; ++q) cc[mi][q] = 0.f;

    // prefetch t = 0
    f4 pf0 = {0,0,0,0}, pf1 = pf0, pf2 = pf0, pf3 = pf0;
    {
        const int col0 = (b * LSEQ + 0) * KC;
        if (pp < 2) {
            const float* s = xarow + col0 + pp * 16;
            pf0 = *(const f4a*)(s);
            pf1 = *(const f4a*)(s + 4);
            pf2 = *(const f4a*)(s + 8);
            pf3 = *(const f4a*)(s + 12);
        } else if (pp == 2) {
            pf0 = *(const f4a*)(xarow + col0);        // cols 0..3
            pf1 = *(const f4a*)(xarow + col0 + 32);   // cols 32..35
        }
    }

    for (int t = 0; t < LSEQ; ++t) {
        __syncthreads();     // prior compute's sXa reads done; drains pf (and WtB DMA at t=0)
        {
            short v[16];
            if (pp < 2) {
#pragma unroll
                for (int e = 0; e < 4; ++e) {
                    v[e]      = bf16hi(pf0[e]);
                    v[4 + e]  = bf16hi(pf1[e]);
                    v[8 + e]  = bf16hi(pf2[e]);
                    v[12 + e] = bf16hi(pf3[e]);
                }
            } else if (pp == 2) {
                v[0] = bf16hi(pf1[0]);
                v[1] = bf16hi(pf1[1]);
                v[2] = bf16hi(pf1[2]);
                v[3] = bf16lo(pf0[0]);
                v[4] = bf16lo(pf0[1]);
                v[5] = bf16lo(pf0[2]);
                v[6] = bf16hi(pf0[0]);
                v[7] = bf16hi(pf0[1]);
                v[8] = bf16hi(pf0[2]);
                v[9]  = bf16hi(1.0f);
                v[10] = bf16hi(rsv);
#pragma unroll
                for (int j = 11; j < 16; ++j) v[j] = bf16hi(narow[j - 11]);
            } else {
#pragma unroll
                for (int j = 0; j < 11; ++j) v[j] = bf16hi(narow[5 + j]);
                v[11] = bf16hi(1.0f);
                v[12] = bf16hi(rsv);
                v[13] = 0; v[14] = 0; v[15] = 0;
            }
#pragma unroll
            for (int q = 0; q < 4; ++q) {
                s16x4 sv = { v[q * 4], v[q * 4 + 1], v[q * 4 + 2], v[q * 4 + 3] };
                *(s16x4*)(wrow + ((pp * 32 + q * 8) ^ wswz)) = sv;
            }
        }
        __syncthreads();     // sXa(t) visible; no outstanding vmem here

        // T14: issue t+1 loads now — latency hides under compute(t)
        if (t + 1 < LSEQ) {
            const int col0 = (b * LSEQ + t + 1) * KC;
            if (pp < 2) {
                const float* s = xarow + col0 + pp * 16;
                pf0 = *(const f4a*)(s);
                pf1 = *(const f4a*)(s + 4);
                pf2 = *(const f4a*)(s + 8);
                pf3 = *(const f4a*)(s + 12);
            } else if (pp == 2) {
                pf0 = *(const f4a*)(xarow + col0);
                pf1 = *(const f4a*)(xarow + col0 + 32);
            }
        }

        s16x8 a0 = *(const s16x8*)(xab + an * 128 + kof0);
        s16x8 a1 = *(const s16x8*)(xab + an * 128 + kof1);
#pragma unroll
        for (int mi = 0; mi < 7; ++mi) {
            const char* bb = wtbb + (mi * 64 + lm) * 128;   // co=0 row; co step = +2048B
            f4 gi = {0.f, 0.f, 0.f, 0.f};
            f4 gf = gi, gg = gi;
            MFMA16(gi, a0, *(const s16x8*)(bb + kof0));
            MFMA16(gi, a1, *(const s16x8*)(bb + kof1));
            MFMA16(gf, a0, *(const s16x8*)(bb + 2048 + kof0));
            MFMA16(gf, a1, *(const s16x8*)(bb + 2048 + kof1));
            MFMA16(gg, a0, *(const s16x8*)(bb + 4096 + kof0));
            MFMA16(gg, a1, *(const s16x8*)(bb + 4096 + kof1));
#pragma unroll
            for (int q = 0; q < 4; ++q) {
                float si = sigf_(gi[q]);
                float sf = sigf_(gf[q]);
                float tg = tanhf_(gg[q]);
                cc[mi][q] = sf * cc[mi][q] + si * tg;
            }
            if (t == LSEQ - 1) {
                f4 go = {0.f, 0.f, 0.f, 0.f};
                MFMA16(go, a0, *(const s16x8*)(bb + 6144 + kof0));
                MFMA16(go, a1, *(const s16x8*)(bb + 6144 + kof1));
#pragma unroll
                for (int q = 0; q < 4; ++q) {
                    float h = sigf_(go[q]) * tanhf_(cc[mi][q]);
                    Hout[((size_t)b * N_NODES + n0 + w * 16 + (l >> 4) * 4 + q) * MDIM
                         + mi * 16 + lm] = h;
                }
            }
        }
    }
}

// ---------------------------------------------------------------------------
// K9: fused decoder, f4-vectorized H loads.
// ---------------------------------------------------------------------------
__global__ void decode_kernel(const float* __restrict__ H,
                              const float* __restrict__ Wdec,
                              const float* __restrict__ bdec,
                              const float* __restrict__ Wout,
                              const float* __restrict__ bout,
                              float* __restrict__ out)
{
    int g = blockIdx.x * 256 + threadIdx.x;   // g = b*2048 + n
    if (g >= BATCH * N_NODES) return;
    int b = g >> 11;
    int n = g & 2047;
    const f4* h0 = (const f4*)(H + (size_t)g * MDIM);
    const f4* h1 = (const f4*)(H + (size_t)BATCH * N_NODES * MDIM + (size_t)g * MDIM);
    float x[12];
#pragma unroll
    for (int o = 0; o < 12; ++o) x[o] = bdec[o];
    for (int mq = 0; mq < 28; ++mq) {
        f4 a0 = h0[mq], a1 = h1[mq];
#pragma unroll
        for (int e = 0; e < 4; ++e) {
            int m = mq * 4 + e;
#pragma unroll
            for (int o = 0; o < 12; ++o)
                x[o] += a0[e] * Wdec[(o * 3 + 0) * MDIM + m]
                      + a1[e] * (Wdec[(o * 3 + 1) * MDIM + m] + Wdec[(o * 3 + 2) * MDIM + m]);
        }
    }
#pragma unroll
    for (int p = 0; p < 12; ++p) {
        float s = bout[p];
#pragma unroll
        for (int o = 0; o < 12; ++o) s += Wout[p * 12 + o] * x[o];
        out[((size_t)b * 12 + p) * N_NODES + n] = s;
    }
}

// ---------------------------------------------------------------------------
extern "C" void kernel_launch(void* const* d_in, const int* in_sizes, int n_in,
                              void* d_out, int out_size, void* d_ws, size_t ws_size,
                              hipStream_t stream)
{
    const float* hist   = (const float*)d_in[0];
    const float* adj    = (const float*)d_in[1];
    const float* node_e = (const float*)d_in[2];
    const float* tid_e  = (const float*)d_in[3];
    const float* diw_e  = (const float*)d_in[4];
    const float* W_in   = (const float*)d_in[5];
    const float* b_in   = (const float*)d_in[6];
    const float* W_pre  = (const float*)d_in[7];
    const float* b_pre  = (const float*)d_in[8];
    const float* E_dy   = (const float*)d_in[9];
    const float* W_dy   = (const float*)d_in[10];
    const float* b_dy   = (const float*)d_in[11];
    const float* W_dec  = (const float*)d_in[12];
    const float* b_dec  = (const float*)d_in[13];
    const float* W_out  = (const float*)d_in[14];
    const float* b_out  = (const float*)d_in[15];
    float* out = (float*)d_out;

    float* ws = (float*)d_ws;
    const size_t XA_F   = (size_t)4096 * NCOLS_X;            // 27,787,264 floats
    const size_t ABIG_F = (size_t)4096 * KBIG / 2;           //  4,194,304 float-equiv
    const size_t XT_F   = (size_t)NCOLS_X * KBIG / 2;        //  6,946,816 float-equiv

    float* XA    = ws;                        // [4096][NCOLS_X]
    float* AbigF = ws + XA_F;
    __hip_bfloat16* Abig = (__hip_bfloat16*)AbigF;
    float* H     = AbigF;                     // aliases Abig+XT (dead after gemm)
    __hip_bfloat16* XTc = (__hip_bfloat16*)(ws + XA_F + ABIG_F);
    float* tail = ws + XA_F + ABIG_F + XT_F;
    float* na_pre = tail;                     tail += (size_t)N_NODES * 16;
    float* na_dy  = tail;                     tail += (size_t)N_NODES * 16;
    float* rs_pre = tail;                     tail += N_NODES;
    float* rs_dy  = tail;                     tail += N_NODES;
    float* Wt_pre = tail;                     tail += (size_t)KC * GDIM;
    float* Wt_dy  = tail;                     tail += (size_t)KC * GDIM;
    float* bW_pre = tail;                     tail += GDIM;
    float* bW_dy  = tail;                     tail += GDIM;
    short* WtBg   = (short*)tail;             // 2 * WTB_SH shorts

    // dynamic adjacency rows go straight into Abig (bf16)
    adaptive_adj_kernel<<<N_NODES, 256, 0, stream>>>(E_dy, node_e, Abig, na_dy, rs_dy);
    node_rs_kernel<<<N_NODES, 256, 0, stream>>>(adj, node_e, na_pre, rs_pre);
    prep_wt_kernel<<<2, 256, 0, stream>>>(W_in, b_in, W_pre, Wt_pre, bW_pre);
    prep_wt_kernel<<<2, 256, 0, stream>>>(W_in, b_in, W_dy, Wt_dy, bW_dy);
    wtb_pack_kernel<<<(GDIM * KL + 255) / 256, 256, 0, stream>>>(
        Wt_pre, bW_pre, b_pre, W_pre, WtBg);
    wtb_pack_kernel<<<(GDIM * KL + 255) / 256, 256, 0, stream>>>(
        Wt_dy, bW_dy, b_dy, W_dy, WtBg + WTB_SH);

    // predefined-adjacency half of Abig, full-N build, ONE 256x128-tiled GEMM
    pack_a_kernel<<<(2048 * 2048 / 4) / 256, 256, 0, stream>>>(adj, Abig);
    build_xt_kernel<<<(NCOLS_X * 2048 / 4) / 256, 256, 0, stream>>>(hist, tid_e, diw_e, XTc);
    gemm_bf16_kernel<<<dim3(53, 16), 512, 0, stream>>>(
        (const short*)Abig, (const short*)XTc, XA);

    // fused MFMA gates + recurrence (H overwrites dead Abig/XT region)
    lstm5_kernel<<<dim3(N_NODES / 128, BATCH, 2), 512, 0, stream>>>(
        XA, WtBg, na_pre, na_dy, rs_pre, rs_dy, H);

    decode_kernel<<<(BATCH * N_NODES + 255) / 256, 256, 0, stream>>>(
        H, W_dec, b_dec, W_out, b_out, out);
}